// Round 2
// baseline (4618.866 us; speedup 1.0000x reference)
//
#include <hip/hip_runtime.h>
#include <hip/hip_bf16.h>

#define B_ 4
#define S_ 96
#define T_ 96
#define D_ 512
#define H_ 8
#define FF_ 2048
#define NROWS (B_*S_*T_)   // 36864
#define EPS_ 1e-5f
#define NEG_ 0.01f

typedef unsigned short u16;   // bf16 bits

__device__ __forceinline__ float bf(u16 u) { return __uint_as_float(((unsigned)u) << 16); }
__device__ __forceinline__ unsigned f2bfbits(float f) {
    unsigned x = __float_as_uint(f);
    return (x + 0x7fffu + ((x >> 16) & 1u)) >> 16;   // RNE
}
__device__ __forceinline__ float blo(unsigned v) { return __uint_as_float(v << 16); }
__device__ __forceinline__ float bhi(unsigned v) { return __uint_as_float(v & 0xffff0000u); }

// ---- dtype helpers ----
__device__ __forceinline__ float4 load4f(const float* p) { return *(const float4*)p; }
__device__ __forceinline__ float4 load4f(const u16* p) {
    ushort4 u = *(const ushort4*)p;
    return make_float4(bf(u.x), bf(u.y), bf(u.z), bf(u.w));
}
__device__ __forceinline__ float cvt_ld(float x) { return x; }
__device__ __forceinline__ float cvt_ld(u16 x)  { return bf(x); }
__device__ __forceinline__ void cvt_st(float* p, float v) { *p = v; }
__device__ __forceinline__ void cvt_st(u16* p, float v)   { *p = (u16)f2bfbits(v); }

__device__ __forceinline__ void load8(const float* p, float* y) {
    float4 a = *(const float4*)p, b = *(const float4*)(p + 4);
    y[0]=a.x; y[1]=a.y; y[2]=a.z; y[3]=a.w; y[4]=b.x; y[5]=b.y; y[6]=b.z; y[7]=b.w;
}
__device__ __forceinline__ void load8(const u16* p, float* y) {
    uint4 u = *(const uint4*)p;
    y[0]=blo(u.x); y[1]=bhi(u.x); y[2]=blo(u.y); y[3]=bhi(u.y);
    y[4]=blo(u.z); y[5]=bhi(u.z); y[6]=blo(u.w); y[7]=bhi(u.w);
}
__device__ __forceinline__ void store8(float* p, const float* y) {
    *(float4*)p       = make_float4(y[0], y[1], y[2], y[3]);
    *(float4*)(p + 4) = make_float4(y[4], y[5], y[6], y[7]);
}
__device__ __forceinline__ void store8(u16* p, const float* y) {
    uint4 u;
    u.x = f2bfbits(y[0]) | (f2bfbits(y[1]) << 16);
    u.y = f2bfbits(y[2]) | (f2bfbits(y[3]) << 16);
    u.z = f2bfbits(y[4]) | (f2bfbits(y[5]) << 16);
    u.w = f2bfbits(y[6]) | (f2bfbits(y[7]) << 16);
    *(uint4*)p = u;
}

// ---------------- GEMM: C = act(A @ W [+ bias | + C_old]) ----------------
// A: (NROWS x K) lda (TA = float|u16), W: (K x M) fp32 ldw, C: (NROWS x ldc) (TC)
// 128x128 tile, TK=8, 256 threads, 8x8 micro-tile per thread.
template<typename TA, typename TC, int ACT, bool ACC>
__global__ __launch_bounds__(256)
void gemm_k(const TA* __restrict__ A, const float* __restrict__ W,
            const float* __restrict__ bias, TC* __restrict__ C,
            int K, int lda, int ldw, int ldc)
{
    __shared__ float As[8][128];
    __shared__ float Bs[8][128];
    const int tid = threadIdx.x;
    const int tx = tid & 15, ty = tid >> 4;
    const int row0 = blockIdx.y * 128, col0 = blockIdx.x * 128;
    float acc[8][8] = {};
    const int ar = tid >> 1, ac = (tid & 1) << 2;   // A-tile: 128 rows x 8 cols
    const int br = tid >> 5, bc = (tid & 31) << 2;  // B-tile: 8 rows x 128 cols

    for (int kt = 0; kt < K; kt += 8) {
        float4 av = load4f(A + (size_t)(row0 + ar) * lda + kt + ac);
        As[ac + 0][ar] = av.x; As[ac + 1][ar] = av.y;
        As[ac + 2][ar] = av.z; As[ac + 3][ar] = av.w;
        *reinterpret_cast<float4*>(&Bs[br][bc]) =
            *reinterpret_cast<const float4*>(W + (size_t)(kt + br) * ldw + col0 + bc);
        __syncthreads();
#pragma unroll
        for (int k = 0; k < 8; ++k) {
            float a[8], b[8];
#pragma unroll
            for (int i = 0; i < 8; ++i) a[i] = As[k][ty + 16 * i];
#pragma unroll
            for (int j = 0; j < 8; ++j) b[j] = Bs[k][tx + 16 * j];
#pragma unroll
            for (int i = 0; i < 8; ++i)
#pragma unroll
                for (int j = 0; j < 8; ++j)
                    acc[i][j] = fmaf(a[i], b[j], acc[i][j]);
        }
        __syncthreads();
    }
#pragma unroll
    for (int i = 0; i < 8; ++i) {
        const size_t r = (size_t)row0 + ty + 16 * i;
#pragma unroll
        for (int j = 0; j < 8; ++j) {
            const int c = col0 + tx + 16 * j;
            float v = acc[i][j];
            if (ACC) v += cvt_ld(C[r * ldc + c]);
            else     v += bias[c];
            if (ACT == 1) v = (v >= 0.f) ? v : NEG_ * v;
            cvt_st(&C[r * ldc + c], v);
        }
    }
}

// ---------------- Attention core (bf16 qkv in, bf16 out) ----------------
// qkv rows (NROWS x 1536): [q(512)|k(512)|v(512)]. One block per (b,h,group).
// time_axis=1: group=(b,s), seq over t (stride 1). 0: group=(b,t), seq over s (stride 96).
__global__ __launch_bounds__(128)
void attn(const u16* __restrict__ qkv, const float* __restrict__ mask,
          u16* __restrict__ out, int time_axis)
{
    __shared__ float Ks[96][64];
    __shared__ float Vs[96][64];
    const int g = blockIdx.x;
    const int h = g & 7;
    const int bs = g >> 3;
    const int b = bs / 96, st = bs % 96;
    const size_t base   = time_axis ? ((size_t)(b * 96 + st) * 96) : ((size_t)b * 96 * 96 + st);
    const size_t stride = time_axis ? 1 : 96;
    const int tid = threadIdx.x;

    for (int e4 = tid; e4 < 96 * 16; e4 += 128) {
        const int r = e4 >> 4, d4 = (e4 & 15) << 2;
        const u16* p = qkv + (base + (size_t)r * stride) * 1536 + h * 64 + d4;
        ushort4 ku = *(const ushort4*)(p + 512);
        ushort4 vu = *(const ushort4*)(p + 1024);
        Ks[r][d4]     = bf(ku.x); Ks[r][d4 + 1] = bf(ku.y);
        Ks[r][d4 + 2] = bf(ku.z); Ks[r][d4 + 3] = bf(ku.w);
        Vs[r][d4]     = bf(vu.x); Vs[r][d4 + 1] = bf(vu.y);
        Vs[r][d4 + 2] = bf(vu.z); Vs[r][d4 + 3] = bf(vu.w);
    }
    __syncthreads();
    if (tid >= 96) return;

    const size_t qrow = base + (size_t)tid * stride;
    const u16* qp = qkv + qrow * 1536 + h * 64;
    float q[64];
#pragma unroll
    for (int d4 = 0; d4 < 64; d4 += 4) {
        ushort4 u = *(const ushort4*)(qp + d4);
        q[d4] = bf(u.x); q[d4 + 1] = bf(u.y); q[d4 + 2] = bf(u.z); q[d4 + 3] = bf(u.w);
    }
    float m = -1e30f, l = 0.f;
    for (int u = 0; u < 96; ++u) {
        float s = 0.f;
#pragma unroll
        for (int d4 = 0; d4 < 64; d4 += 4) {
            float4 kv = *(const float4*)&Ks[u][d4];
            s = fmaf(q[d4], kv.x, fmaf(q[d4 + 1], kv.y,
                fmaf(q[d4 + 2], kv.z, fmaf(q[d4 + 3], kv.w, s))));
        }
        s *= 0.125f;
        const float nm = fmaxf(m, s);
        l = l * __expf(m - nm) + __expf(s - nm);
        m = nm;
    }
    const float inv_l = 1.f / l;
    float o[64];
#pragma unroll
    for (int d = 0; d < 64; ++d) o[d] = 0.f;
    for (int u = 0; u < 96; ++u) {
        float s = 0.f;
#pragma unroll
        for (int d4 = 0; d4 < 64; d4 += 4) {
            float4 kv = *(const float4*)&Ks[u][d4];
            s = fmaf(q[d4], kv.x, fmaf(q[d4 + 1], kv.y,
                fmaf(q[d4 + 2], kv.z, fmaf(q[d4 + 3], kv.w, s))));
        }
        const float p = __expf(s * 0.125f - m) * inv_l;
#pragma unroll
        for (int d4 = 0; d4 < 64; d4 += 4) {
            float4 vv = *(const float4*)&Vs[u][d4];
            o[d4]     = fmaf(p, vv.x, o[d4]);
            o[d4 + 1] = fmaf(p, vv.y, o[d4 + 1]);
            o[d4 + 2] = fmaf(p, vv.z, o[d4 + 2]);
            o[d4 + 3] = fmaf(p, vv.w, o[d4 + 3]);
        }
    }
    const float mk = mask[qrow];
    u16* op = out + qrow * 512 + h * 64;
#pragma unroll
    for (int d4 = 0; d4 < 64; d4 += 4) {
        unsigned lo = f2bfbits(o[d4] * mk)     | (f2bfbits(o[d4 + 1] * mk) << 16);
        unsigned hi = f2bfbits(o[d4 + 2] * mk) | (f2bfbits(o[d4 + 3] * mk) << 16);
        *(uint2*)(op + d4) = make_uint2(lo, hi);
    }
}

// ---------------- residual add + LayerNorm (one wave per row of 512) ----------------
template<typename TA, typename TB, typename TO>
__global__ __launch_bounds__(64)
void add_ln(const TA* __restrict__ a, const TB* __restrict__ bsrc,
            const float* __restrict__ g, const float* __restrict__ beta,
            TO* __restrict__ out)
{
    const size_t row = blockIdx.x;
    const int lane = threadIdx.x;
    float ya[8], yb[8], y[8];
    load8(a + row * D_ + lane * 8, ya);
    load8(bsrc + row * D_ + lane * 8, yb);
    float sum = 0.f, sq = 0.f;
#pragma unroll
    for (int i = 0; i < 8; ++i) { y[i] = ya[i] + yb[i]; sum += y[i]; sq += y[i] * y[i]; }
#pragma unroll
    for (int off = 32; off >= 1; off >>= 1) {
        sum += __shfl_xor(sum, off);
        sq  += __shfl_xor(sq, off);
    }
    const float mean = sum * (1.f / D_);
    const float var  = sq * (1.f / D_) - mean * mean;
    const float rstd = rsqrtf(var + EPS_);
    const float* gp = g + lane * 8;
    const float* bp = beta + lane * 8;
    float o[8];
#pragma unroll
    for (int i = 0; i < 8; ++i) o[i] = (y[i] - mean) * rstd * gp[i] + bp[i];
    store8(out + row * D_ + lane * 8, o);
}

extern "C" void kernel_launch(void* const* d_in, const int* in_sizes, int n_in,
                              void* d_out, int out_size, void* d_ws, size_t ws_size,
                              hipStream_t stream)
{
    const float* x     = (const float*)d_in[0];
    const float* mask  = (const float*)d_in[1];
    const float* t_w   = (const float*)d_in[2];
    const float* t_b   = (const float*)d_in[3];
    const float* s_w   = (const float*)d_in[4];
    const float* s_b   = (const float*)d_in[5];
    const float* fc_w1 = (const float*)d_in[6];
    const float* fc_b1 = (const float*)d_in[7];
    const float* fc_w2 = (const float*)d_in[8];
    const float* fc_b2 = (const float*)d_in[9];
    const float* ln1_g = (const float*)d_in[10];
    const float* ln1_b = (const float*)d_in[11];
    const float* ln2_g = (const float*)d_in[12];
    const float* ln2_b = (const float*)d_in[13];

    // Workspace: one bf16 buffer NROWS x 1536 (108 MB).
    //   full:        qkv staging (both MHAs)
    //   FFN phase:   [0:512)=h chunk, [512:1024)=ff accum, [1024:1536)=x1
    // d_out (75.5 MB fp32) doubles as bf16 scratch: lo = attn-out, hi = tt/ss.
    const size_t WS_ELEMS = (size_t)NROWS * 1536;
    if (ws_size < WS_ELEMS * sizeof(u16)) return;  // diagnostic: absmax-fail => ws too small
    u16* WS    = (u16*)d_ws;
    u16* hch   = WS;
    u16* ffb   = WS + (size_t)NROWS * 512;
    u16* x1    = WS + (size_t)NROWS * 1024;
    u16* OUTlo = (u16*)d_out;
    u16* OUThi = OUTlo + (size_t)NROWS * 512;
    const size_t DD = (size_t)D_ * D_;

    const dim3 blk(256);
    const dim3 g512(4, NROWS / 128);

    // ---- time MHA ----
    for (int i = 0; i < 3; ++i)
        gemm_k<float, u16, 0, false><<<g512, blk, 0, stream>>>(
            x, t_w + i * DD, t_b + i * D_, WS + i * D_, D_, D_, D_, 3 * D_);
    attn<<<dim3(B_ * H_ * S_), dim3(128), 0, stream>>>(WS, mask, OUTlo, 1);
    gemm_k<u16, u16, 0, false><<<g512, blk, 0, stream>>>(
        OUTlo, t_w + 3 * DD, t_b + 3 * D_, OUThi, D_, D_, D_, D_);          // tt
    // ---- space MHA ----
    for (int i = 0; i < 3; ++i)
        gemm_k<u16, u16, 0, false><<<g512, blk, 0, stream>>>(
            OUThi, s_w + i * DD, s_b + i * D_, WS + i * D_, D_, D_, D_, 3 * D_);
    attn<<<dim3(B_ * H_ * T_), dim3(128), 0, stream>>>(WS, mask, OUTlo, 0);
    gemm_k<u16, u16, 0, false><<<g512, blk, 0, stream>>>(
        OUTlo, s_w + 3 * DD, s_b + 3 * D_, OUThi, D_, D_, D_, D_);          // ss
    // ---- LN1: x1 = LN(x + ss) ----
    add_ln<float, u16, u16><<<dim3(NROWS), dim3(64), 0, stream>>>(x, OUThi, ln1_g, ln1_b, x1);
    // ---- FFN, chunked over FF in 4 x 512 columns ----
    for (int c = 0; c < 4; ++c) {
        gemm_k<u16, u16, 1, false><<<g512, blk, 0, stream>>>(
            x1, fc_w1 + c * 512, fc_b1 + c * 512, hch, D_, D_, FF_, D_);    // leaky(h chunk)
        if (c == 0)
            gemm_k<u16, u16, 0, false><<<g512, blk, 0, stream>>>(
                hch, fc_w2 + (size_t)c * 512 * D_, fc_b2, ffb, 512, D_, D_, D_);
        else
            gemm_k<u16, u16, 0, true><<<g512, blk, 0, stream>>>(
                hch, fc_w2 + (size_t)c * 512 * D_, nullptr, ffb, 512, D_, D_, D_);
    }
    // ---- LN2: out = LN(x1 + ff) -> fp32 d_out ----
    add_ln<u16, u16, float><<<dim3(NROWS), dim3(64), 0, stream>>>(
        x1, ffb, ln2_g, ln2_b, (float*)d_out);
}

// Round 3
// 1169.847 us; speedup vs baseline: 3.9483x; 3.9483x over previous
//
#include <hip/hip_runtime.h>
#include <hip/hip_bf16.h>

#define B_ 4
#define S_ 96
#define T_ 96
#define D_ 512
#define H_ 8
#define FF_ 2048
#define NROWS (B_*S_*T_)   // 36864
#define EPS_ 1e-5f
#define NEG_ 0.01f
#define DD_ (512*512)

typedef unsigned short u16;   // bf16 bits
typedef __attribute__((ext_vector_type(8))) short bf16x8;
typedef __attribute__((ext_vector_type(4))) float f32x4;
typedef __attribute__((address_space(1))) const unsigned glb_u32;
typedef __attribute__((address_space(3))) unsigned lds_u32;

__device__ __forceinline__ float bf(u16 u) { return __uint_as_float(((unsigned)u) << 16); }
__device__ __forceinline__ unsigned f2bfbits(float f) {
    unsigned x = __float_as_uint(f);
    return (x + 0x7fffu + ((x >> 16) & 1u)) >> 16;   // RNE
}
__device__ __forceinline__ float blo(unsigned v) { return __uint_as_float(v << 16); }
__device__ __forceinline__ float bhi(unsigned v) { return __uint_as_float(v & 0xffff0000u); }

__device__ __forceinline__ void load8(const float* p, float* y) {
    float4 a = *(const float4*)p, b = *(const float4*)(p + 4);
    y[0]=a.x; y[1]=a.y; y[2]=a.z; y[3]=a.w; y[4]=b.x; y[5]=b.y; y[6]=b.z; y[7]=b.w;
}
__device__ __forceinline__ void load8(const u16* p, float* y) {
    uint4 u = *(const uint4*)p;
    y[0]=blo(u.x); y[1]=bhi(u.x); y[2]=blo(u.y); y[3]=bhi(u.y);
    y[4]=blo(u.z); y[5]=bhi(u.z); y[6]=blo(u.w); y[7]=bhi(u.w);
}
__device__ __forceinline__ void store8(float* p, const float* y) {
    *(float4*)p       = make_float4(y[0], y[1], y[2], y[3]);
    *(float4*)(p + 4) = make_float4(y[4], y[5], y[6], y[7]);
}
__device__ __forceinline__ void store8(u16* p, const float* y) {
    uint4 u;
    u.x = f2bfbits(y[0]) | (f2bfbits(y[1]) << 16);
    u.y = f2bfbits(y[2]) | (f2bfbits(y[3]) << 16);
    u.z = f2bfbits(y[4]) | (f2bfbits(y[5]) << 16);
    u.w = f2bfbits(y[6]) | (f2bfbits(y[7]) << 16);
    *(uint4*)p = u;
}

// ---------------- fp32 -> bf16 elementwise ----------------
__global__ __launch_bounds__(256)
void cvt_f32_bf16(const float* __restrict__ in, u16* __restrict__ out)
{
    const size_t i = ((size_t)blockIdx.x * 256 + threadIdx.x) * 8;
    float y[8];
    load8(in + i, y);
    store8(out + i, y);
}

// ---------------- transpose + convert: out[C x R] bf16 = in[R x C]^T ----------------
__global__ __launch_bounds__(256)
void tconv(const float* __restrict__ in, u16* __restrict__ out, int R, int C)
{
    __shared__ float t[32][33];
    const int c0 = blockIdx.x * 32, r0 = blockIdx.y * 32;
    const int tr = threadIdx.x >> 3, c4 = (threadIdx.x & 7) * 4;
    float4 v = *(const float4*)(in + (size_t)(r0 + tr) * C + c0 + c4);
    t[tr][c4] = v.x; t[tr][c4 + 1] = v.y; t[tr][c4 + 2] = v.z; t[tr][c4 + 3] = v.w;
    __syncthreads();
    const int oc = tr, r4 = c4;
    ushort4 u;
    u.x = (u16)f2bfbits(t[r4 + 0][oc]); u.y = (u16)f2bfbits(t[r4 + 1][oc]);
    u.z = (u16)f2bfbits(t[r4 + 2][oc]); u.w = (u16)f2bfbits(t[r4 + 3][oc]);
    *(ushort4*)(out + (size_t)(c0 + oc) * R + r0 + r4) = u;
}

// ---------------- MFMA GEMM: C = act(A @ W^T^T [+ bias | + C_old]) ----------------
// A: (NROWS x 512) bf16 lda=512. WT: (512 x K) bf16, row n holds W[:,n] (ld = ldwt).
// C: (NROWS x 512) bf16. Fixed: M=NROWS, N=512, K=512. Grid (4, 288), 256 thr.
// 128x128 tile, BK=64, 4 waves each computing a 64x64 sub-tile (4x4 x 16x16 frags).
// LDS: both tiles stored [line][64] (A-lines = rows, B-lines = cols), staged with
// global_load_lds width 16 (linear dest = line-major; per-lane global src).
template<int ACT, bool ACC>
__global__ __launch_bounds__(256)
void gemm_mfma(const u16* __restrict__ A, const u16* __restrict__ WT,
               const float* __restrict__ bias, u16* __restrict__ C, int ldwt)
{
    __shared__ u16 As[128 * 64];
    __shared__ u16 Bs[128 * 64];
    const int tid = threadIdx.x;
    const int w = tid >> 6, l = tid & 63;
    const int wr = w >> 1, wc = w & 1;
    const int row0 = blockIdx.y * 128, col0 = blockIdx.x * 128;
    const int lrow = l >> 3;           // staging: line within 8-line group
    const int lk8  = (l & 7) * 8;      // staging: k-element offset
    const int fline = l & 15;          // frag: line within 16
    const int fk    = (l >> 4) * 8;    // frag: k base

    f32x4 acc[4][4] = {};

    for (int kt = 0; kt < 512; kt += 64) {
#pragma unroll
        for (int j = 0; j < 4; ++j) {
            const int line = w * 32 + j * 8;
            const u16* asrc = A  + (size_t)(row0 + line + lrow) * 512 + kt + lk8;
            const u16* bsrc = WT + (size_t)(col0 + line + lrow) * ldwt + kt + lk8;
            __builtin_amdgcn_global_load_lds((glb_u32*)asrc, (lds_u32*)&As[line * 64], 16, 0, 0);
            __builtin_amdgcn_global_load_lds((glb_u32*)bsrc, (lds_u32*)&Bs[line * 64], 16, 0, 0);
        }
        __syncthreads();
#pragma unroll
        for (int kk = 0; kk < 2; ++kk) {
            bf16x8 af[4], bfr[4];
#pragma unroll
            for (int i = 0; i < 4; ++i)
                af[i] = *(bf16x8*)&As[(wr * 64 + i * 16 + fline) * 64 + kk * 32 + fk];
#pragma unroll
            for (int j = 0; j < 4; ++j)
                bfr[j] = *(bf16x8*)&Bs[(wc * 64 + j * 16 + fline) * 64 + kk * 32 + fk];
#pragma unroll
            for (int i = 0; i < 4; ++i)
#pragma unroll
                for (int j = 0; j < 4; ++j)
                    acc[i][j] = __builtin_amdgcn_mfma_f32_16x16x32_bf16(af[i], bfr[j], acc[i][j], 0, 0, 0);
        }
        __syncthreads();
    }
    // epilogue: C/D layout col = lane&15, row = (lane>>4)*4 + e
    const int crow = (l >> 4) * 4;
    const int ccol = l & 15;
#pragma unroll
    for (int i = 0; i < 4; ++i) {
#pragma unroll
        for (int j = 0; j < 4; ++j) {
            const int col = col0 + wc * 64 + j * 16 + ccol;
            const float bv = ACC ? 0.f : bias[col];
#pragma unroll
            for (int e = 0; e < 4; ++e) {
                const size_t r = (size_t)(row0 + wr * 64 + i * 16 + crow + e);
                u16* cp = &C[r * 512 + col];
                float v = acc[i][j][e] + bv;
                if (ACC) v += bf(*cp);
                if (ACT == 1) v = (v >= 0.f) ? v : NEG_ * v;
                *cp = (u16)f2bfbits(v);
            }
        }
    }
}

// ---------------- Attention (bf16 q/k/v pages, lda 512) ----------------
// One block per (b,h,group). 1-pass online softmax, K/V chunked 48 rows (24KB LDS).
__global__ __launch_bounds__(128)
void attn(const u16* __restrict__ q, const u16* __restrict__ kbuf,
          const u16* __restrict__ vbuf, const float* __restrict__ mask,
          u16* __restrict__ out, int time_axis)
{
    __shared__ float Ks[48][64];
    __shared__ float Vs[48][64];
    const int g = blockIdx.x;
    const int h = g & 7;
    const int bs = g >> 3;
    const int b = bs / 96, st = bs % 96;
    const size_t base   = time_axis ? ((size_t)(b * 96 + st) * 96) : ((size_t)b * 9216 + st);
    const size_t stride = time_axis ? 1 : 96;
    const int tid = threadIdx.x;

    float qr[64], o[64];
    float m = -1e30f, lsum = 0.f;
    size_t qrow = 0;
    if (tid < 96) {
        qrow = base + (size_t)tid * stride;
        const u16* qp = q + qrow * 512 + h * 64;
#pragma unroll
        for (int d = 0; d < 64; d += 8) load8(qp + d, qr + d);
#pragma unroll
        for (int d = 0; d < 64; ++d) o[d] = 0.f;
    }
    for (int c = 0; c < 2; ++c) {
        __syncthreads();
        for (int e = tid; e < 48 * 8; e += 128) {
            const int r = e >> 3, d8 = (e & 7) * 8;
            const size_t rowi = (base + (size_t)(c * 48 + r) * stride) * 512 + h * 64 + d8;
            float tmp[8];
            load8(kbuf + rowi, tmp);
            store8(&Ks[r][d8], tmp);
            load8(vbuf + rowi, tmp);
            store8(&Vs[r][d8], tmp);
        }
        __syncthreads();
        if (tid < 96) {
            for (int u = 0; u < 48; ++u) {
                float s = 0.f;
#pragma unroll
                for (int d4 = 0; d4 < 64; d4 += 4) {
                    float4 kv = *(const float4*)&Ks[u][d4];
                    s = fmaf(qr[d4], kv.x, fmaf(qr[d4 + 1], kv.y,
                        fmaf(qr[d4 + 2], kv.z, fmaf(qr[d4 + 3], kv.w, s))));
                }
                s *= 0.125f;
                if (s > m + 8.f) {                 // defer-max rescale (rare)
                    const float sc = __expf(m - s);
                    lsum *= sc;
#pragma unroll
                    for (int d = 0; d < 64; ++d) o[d] *= sc;
                    m = s;
                }
                const float p = __expf(s - m);
                lsum += p;
#pragma unroll
                for (int d4 = 0; d4 < 64; d4 += 4) {
                    float4 vv = *(const float4*)&Vs[u][d4];
                    o[d4]     = fmaf(p, vv.x, o[d4]);
                    o[d4 + 1] = fmaf(p, vv.y, o[d4 + 1]);
                    o[d4 + 2] = fmaf(p, vv.z, o[d4 + 2]);
                    o[d4 + 3] = fmaf(p, vv.w, o[d4 + 3]);
                }
            }
        }
    }
    if (tid < 96) {
        const float f = mask[qrow] / lsum;
        u16* op = out + qrow * 512 + h * 64;
#pragma unroll
        for (int d = 0; d < 64; d += 8) {
            float tmp[8];
#pragma unroll
            for (int j = 0; j < 8; ++j) tmp[j] = o[d + j] * f;
            store8(op + d, tmp);
        }
    }
}

// ---------------- residual add + LayerNorm (one wave per row of 512) ----------------
template<typename TA, typename TB, typename TO>
__global__ __launch_bounds__(64)
void add_ln(const TA* __restrict__ a, const TB* __restrict__ bsrc,
            const float* __restrict__ g, const float* __restrict__ beta,
            TO* __restrict__ out)
{
    const size_t row = blockIdx.x;
    const int lane = threadIdx.x;
    float ya[8], yb[8], y[8];
    load8(a + row * D_ + lane * 8, ya);
    load8(bsrc + row * D_ + lane * 8, yb);
    float sum = 0.f, sq = 0.f;
#pragma unroll
    for (int i = 0; i < 8; ++i) { y[i] = ya[i] + yb[i]; sum += y[i]; sq += y[i] * y[i]; }
#pragma unroll
    for (int off = 32; off >= 1; off >>= 1) {
        sum += __shfl_xor(sum, off);
        sq  += __shfl_xor(sq, off);
    }
    const float mean = sum * (1.f / D_);
    const float var  = sq * (1.f / D_) - mean * mean;
    const float rstd = rsqrtf(var + EPS_);
    const float* gp = g + lane * 8;
    const float* bp = beta + lane * 8;
    float o[8];
#pragma unroll
    for (int i = 0; i < 8; ++i) o[i] = (y[i] - mean) * rstd * gp[i] + bp[i];
    store8(out + row * D_ + lane * 8, o);
}

extern "C" void kernel_launch(void* const* d_in, const int* in_sizes, int n_in,
                              void* d_out, int out_size, void* d_ws, size_t ws_size,
                              hipStream_t stream)
{
    const float* x     = (const float*)d_in[0];
    const float* mask  = (const float*)d_in[1];
    const float* t_w   = (const float*)d_in[2];
    const float* t_b   = (const float*)d_in[3];
    const float* s_w   = (const float*)d_in[4];
    const float* s_b   = (const float*)d_in[5];
    const float* fc_w1 = (const float*)d_in[6];
    const float* fc_b1 = (const float*)d_in[7];
    const float* fc_w2 = (const float*)d_in[8];
    const float* fc_b2 = (const float*)d_in[9];
    const float* ln1_g = (const float*)d_in[10];
    const float* ln1_b = (const float*)d_in[11];
    const float* ln2_g = (const float*)d_in[12];
    const float* ln2_b = (const float*)d_in[13];

    // 5 bf16 "pages" of NROWS x 512: WS0,WS1,WS2 in d_ws; O0,O1 in d_out.
    // Phase-scheduled: xb->WS2; WB1(t_w0..2)->O1; q/att->O0,k->WS0,v->WS1; tt/ss->O1;
    // WB2(t_w3,s_w0..3)->WS2; x1->WS0; WB3(fc WTs)->O0; h->WS1; ff->WS2.
    const size_t PG = (size_t)NROWS * 512;
    if (ws_size < PG * 3 * sizeof(u16)) return;   // diagnostic: abs-fail => ws too small
    u16* O0  = (u16*)d_out;
    u16* O1  = O0 + PG;
    u16* WS0 = (u16*)d_ws;
    u16* WS1 = WS0 + PG;
    u16* WS2 = WS1 + PG;

    const dim3 gblk(256);
    const dim3 ggrid(4, NROWS / 128);
    const dim3 t512(16, 16);

    // x -> bf16 (WS2)
    cvt_f32_bf16<<<dim3((unsigned)(PG / 2048)), gblk, 0, stream>>>(x, WS2);
    // t_w[0..2] -> WT bf16 in O1
    for (int i = 0; i < 3; ++i)
        tconv<<<t512, gblk, 0, stream>>>(t_w + (size_t)i * DD_, O1 + (size_t)i * DD_, 512, 512);
    // time QKV
    u16* qkvp[3] = { O0, WS0, WS1 };
    for (int i = 0; i < 3; ++i)
        gemm_mfma<0, false><<<ggrid, gblk, 0, stream>>>(
            WS2, O1 + (size_t)i * DD_, t_b + i * 512, qkvp[i], 512);
    // t_w3, s_w0..3 -> WT bf16 in WS2 (xb dead)
    tconv<<<t512, gblk, 0, stream>>>(t_w + (size_t)3 * DD_, WS2, 512, 512);
    for (int i = 0; i < 4; ++i)
        tconv<<<t512, gblk, 0, stream>>>(s_w + (size_t)i * DD_, WS2 + (size_t)(1 + i) * DD_, 512, 512);
    attn<<<dim3(B_ * H_ * 96), dim3(128), 0, stream>>>(O0, WS0, WS1, mask, O0, 1);
    gemm_mfma<0, false><<<ggrid, gblk, 0, stream>>>(O0, WS2, t_b + 3 * 512, O1, 512);      // tt
    // space QKV
    for (int i = 0; i < 3; ++i)
        gemm_mfma<0, false><<<ggrid, gblk, 0, stream>>>(
            O1, WS2 + (size_t)(1 + i) * DD_, s_b + i * 512, qkvp[i], 512);
    attn<<<dim3(B_ * H_ * 96), dim3(128), 0, stream>>>(O0, WS0, WS1, mask, O0, 0);
    gemm_mfma<0, false><<<ggrid, gblk, 0, stream>>>(O0, WS2 + (size_t)4 * DD_, s_b + 3 * 512, O1, 512); // ss
    // LN1: x1 = LN(x + ss) -> WS0
    add_ln<float, u16, u16><<<dim3(NROWS), dim3(64), 0, stream>>>(x, O1, ln1_g, ln1_b, WS0);
    // fc WTs -> O0 (att dead): WT1 = fc_w1^T (2048x512), WT2 = fc_w2^T (512x2048)
    u16* WT1 = O0;
    u16* WT2 = O0 + (size_t)2048 * 512;
    tconv<<<dim3(64, 16), gblk, 0, stream>>>(fc_w1, WT1, 512, 2048);
    tconv<<<dim3(16, 64), gblk, 0, stream>>>(fc_w2, WT2, 2048, 512);
    // FFN chunked over FF in 4 x 512
    for (int c = 0; c < 4; ++c) {
        gemm_mfma<1, false><<<ggrid, gblk, 0, stream>>>(
            WS0, WT1 + (size_t)c * 512 * 512, fc_b1 + c * 512, WS1, 512);       // h = leaky
        if (c == 0)
            gemm_mfma<0, false><<<ggrid, gblk, 0, stream>>>(
                WS1, WT2 + (size_t)c * 512, fc_b2, WS2, 2048);
        else
            gemm_mfma<0, true><<<ggrid, gblk, 0, stream>>>(
                WS1, WT2 + (size_t)c * 512, nullptr, WS2, 2048);
    }
    // LN2: out = LN(x1 + ff) -> fp32 d_out (reads WS0/WS2 only)
    add_ln<u16, u16, float><<<dim3(NROWS), dim3(64), 0, stream>>>(
        WS0, WS2, ln2_g, ln2_b, (float*)d_out);
}

// Round 4
// 786.963 us; speedup vs baseline: 5.8692x; 1.4865x over previous
//
#include <hip/hip_runtime.h>
#include <hip/hip_bf16.h>

#define B_ 4
#define S_ 96
#define T_ 96
#define D_ 512
#define H_ 8
#define FF_ 2048
#define NROWS (B_*S_*T_)   // 36864
#define EPS_ 1e-5f
#define NEG_ 0.01f
#define DD_ (512*512)

typedef unsigned short u16;   // bf16 bits
typedef __attribute__((ext_vector_type(8))) short bf16x8;
typedef __attribute__((ext_vector_type(4))) float f32x4;
typedef __attribute__((address_space(1))) const unsigned glb_u32;
typedef __attribute__((address_space(3))) unsigned lds_u32;

__device__ __forceinline__ float bf(u16 u) { return __uint_as_float(((unsigned)u) << 16); }
__device__ __forceinline__ unsigned f2bfbits(float f) {
    unsigned x = __float_as_uint(f);
    return (x + 0x7fffu + ((x >> 16) & 1u)) >> 16;   // RNE
}
__device__ __forceinline__ float blo(unsigned v) { return __uint_as_float(v << 16); }
__device__ __forceinline__ float bhi(unsigned v) { return __uint_as_float(v & 0xffff0000u); }

__device__ __forceinline__ void load8(const float* p, float* y) {
    float4 a = *(const float4*)p, b = *(const float4*)(p + 4);
    y[0]=a.x; y[1]=a.y; y[2]=a.z; y[3]=a.w; y[4]=b.x; y[5]=b.y; y[6]=b.z; y[7]=b.w;
}
__device__ __forceinline__ void load8(const u16* p, float* y) {
    uint4 u = *(const uint4*)p;
    y[0]=blo(u.x); y[1]=bhi(u.x); y[2]=blo(u.y); y[3]=bhi(u.y);
    y[4]=blo(u.z); y[5]=bhi(u.z); y[6]=blo(u.w); y[7]=bhi(u.w);
}
__device__ __forceinline__ void store8(float* p, const float* y) {
    *(float4*)p       = make_float4(y[0], y[1], y[2], y[3]);
    *(float4*)(p + 4) = make_float4(y[4], y[5], y[6], y[7]);
}
__device__ __forceinline__ void store8(u16* p, const float* y) {
    uint4 u;
    u.x = f2bfbits(y[0]) | (f2bfbits(y[1]) << 16);
    u.y = f2bfbits(y[2]) | (f2bfbits(y[3]) << 16);
    u.z = f2bfbits(y[4]) | (f2bfbits(y[5]) << 16);
    u.w = f2bfbits(y[6]) | (f2bfbits(y[7]) << 16);
    *(uint4*)p = u;
}

// ---------------- fp32 -> bf16 elementwise ----------------
__global__ __launch_bounds__(256)
void cvt_f32_bf16(const float* __restrict__ in, u16* __restrict__ out)
{
    const size_t i = ((size_t)blockIdx.x * 256 + threadIdx.x) * 8;
    float y[8];
    load8(in + i, y);
    store8(out + i, y);
}

// ---------------- transpose + convert: out[C x R] bf16 = in[R x C]^T ----------------
__global__ __launch_bounds__(256)
void tconv(const float* __restrict__ in, u16* __restrict__ out, int R, int C)
{
    __shared__ float t[32][33];
    const int c0 = blockIdx.x * 32, r0 = blockIdx.y * 32;
    const int tr = threadIdx.x >> 3, c4 = (threadIdx.x & 7) * 4;
    float4 v = *(const float4*)(in + (size_t)(r0 + tr) * C + c0 + c4);
    t[tr][c4] = v.x; t[tr][c4 + 1] = v.y; t[tr][c4 + 2] = v.z; t[tr][c4 + 3] = v.w;
    __syncthreads();
    const int oc = tr, r4 = c4;
    ushort4 u;
    u.x = (u16)f2bfbits(t[r4 + 0][oc]); u.y = (u16)f2bfbits(t[r4 + 1][oc]);
    u.z = (u16)f2bfbits(t[r4 + 2][oc]); u.w = (u16)f2bfbits(t[r4 + 3][oc]);
    *(ushort4*)(out + (size_t)(c0 + oc) * R + r0 + r4) = u;
}

// ---------------- MFMA GEMM (as round 3, verified) ----------------
template<int ACT, bool ACC>
__global__ __launch_bounds__(256)
void gemm_mfma(const u16* __restrict__ A, const u16* __restrict__ WT,
               const float* __restrict__ bias, u16* __restrict__ C, int ldwt)
{
    __shared__ u16 As[128 * 64];
    __shared__ u16 Bs[128 * 64];
    const int tid = threadIdx.x;
    const int w = tid >> 6, l = tid & 63;
    const int wr = w >> 1, wc = w & 1;
    const int row0 = blockIdx.y * 128, col0 = blockIdx.x * 128;
    const int lrow = l >> 3;
    const int lk8  = (l & 7) * 8;
    const int fline = l & 15;
    const int fk    = (l >> 4) * 8;

    f32x4 acc[4][4] = {};

    for (int kt = 0; kt < 512; kt += 64) {
#pragma unroll
        for (int j = 0; j < 4; ++j) {
            const int line = w * 32 + j * 8;
            const u16* asrc = A  + (size_t)(row0 + line + lrow) * 512 + kt + lk8;
            const u16* bsrc = WT + (size_t)(col0 + line + lrow) * ldwt + kt + lk8;
            __builtin_amdgcn_global_load_lds((glb_u32*)asrc, (lds_u32*)&As[line * 64], 16, 0, 0);
            __builtin_amdgcn_global_load_lds((glb_u32*)bsrc, (lds_u32*)&Bs[line * 64], 16, 0, 0);
        }
        __syncthreads();
#pragma unroll
        for (int kk = 0; kk < 2; ++kk) {
            bf16x8 af[4], bfr[4];
#pragma unroll
            for (int i = 0; i < 4; ++i)
                af[i] = *(bf16x8*)&As[(wr * 64 + i * 16 + fline) * 64 + kk * 32 + fk];
#pragma unroll
            for (int j = 0; j < 4; ++j)
                bfr[j] = *(bf16x8*)&Bs[(wc * 64 + j * 16 + fline) * 64 + kk * 32 + fk];
#pragma unroll
            for (int i = 0; i < 4; ++i)
#pragma unroll
                for (int j = 0; j < 4; ++j)
                    acc[i][j] = __builtin_amdgcn_mfma_f32_16x16x32_bf16(af[i], bfr[j], acc[i][j], 0, 0, 0);
        }
        __syncthreads();
    }
    const int crow = (l >> 4) * 4;
    const int ccol = l & 15;
#pragma unroll
    for (int i = 0; i < 4; ++i) {
#pragma unroll
        for (int j = 0; j < 4; ++j) {
            const int col = col0 + wc * 64 + j * 16 + ccol;
            const float bv = ACC ? 0.f : bias[col];
#pragma unroll
            for (int e = 0; e < 4; ++e) {
                const size_t r = (size_t)(row0 + wr * 64 + i * 16 + crow + e);
                u16* cp = &C[r * 512 + col];
                float v = acc[i][j][e] + bv;
                if (ACC) v += bf(*cp);
                if (ACT == 1) v = (v >= 0.f) ? v : NEG_ * v;
                *cp = (u16)f2bfbits(v);
            }
        }
    }
}

// ---------------- fused QKV GEMM: 3 outputs, WT rows contiguous (1536 x 512) ----------------
// grid (12, 288): page = blockIdx.x>>2 selects c0/c1/c2; bias rows contiguous (3x512).
__global__ __launch_bounds__(256)
void gemm_qkv(const u16* __restrict__ A, const u16* __restrict__ WT,
              const float* __restrict__ bias,
              u16* __restrict__ c0, u16* __restrict__ c1, u16* __restrict__ c2)
{
    __shared__ u16 As[128 * 64];
    __shared__ u16 Bs[128 * 64];
    const int tid = threadIdx.x;
    const int w = tid >> 6, l = tid & 63;
    const int wr = w >> 1, wc = w & 1;
    const int row0 = blockIdx.y * 128;
    const int wtrow0 = blockIdx.x * 128;               // 0..1535
    const int page = blockIdx.x >> 2;
    const int colp0 = (blockIdx.x & 3) * 128;          // col within page
    u16* C = (page == 0) ? c0 : (page == 1) ? c1 : c2;
    const int lrow = l >> 3;
    const int lk8  = (l & 7) * 8;
    const int fline = l & 15;
    const int fk    = (l >> 4) * 8;

    f32x4 acc[4][4] = {};

    for (int kt = 0; kt < 512; kt += 64) {
#pragma unroll
        for (int j = 0; j < 4; ++j) {
            const int line = w * 32 + j * 8;
            const u16* asrc = A  + (size_t)(row0 + line + lrow) * 512 + kt + lk8;
            const u16* bsrc = WT + (size_t)(wtrow0 + line + lrow) * 512 + kt + lk8;
            __builtin_amdgcn_global_load_lds((glb_u32*)asrc, (lds_u32*)&As[line * 64], 16, 0, 0);
            __builtin_amdgcn_global_load_lds((glb_u32*)bsrc, (lds_u32*)&Bs[line * 64], 16, 0, 0);
        }
        __syncthreads();
#pragma unroll
        for (int kk = 0; kk < 2; ++kk) {
            bf16x8 af[4], bfr[4];
#pragma unroll
            for (int i = 0; i < 4; ++i)
                af[i] = *(bf16x8*)&As[(wr * 64 + i * 16 + fline) * 64 + kk * 32 + fk];
#pragma unroll
            for (int j = 0; j < 4; ++j)
                bfr[j] = *(bf16x8*)&Bs[(wc * 64 + j * 16 + fline) * 64 + kk * 32 + fk];
#pragma unroll
            for (int i = 0; i < 4; ++i)
#pragma unroll
                for (int j = 0; j < 4; ++j)
                    acc[i][j] = __builtin_amdgcn_mfma_f32_16x16x32_bf16(af[i], bfr[j], acc[i][j], 0, 0, 0);
        }
        __syncthreads();
    }
    const int crow = (l >> 4) * 4;
    const int ccol = l & 15;
#pragma unroll
    for (int i = 0; i < 4; ++i) {
#pragma unroll
        for (int j = 0; j < 4; ++j) {
            const int col = colp0 + wc * 64 + j * 16 + ccol;
            const float bv = bias[wtrow0 + wc * 64 + j * 16 + ccol];
#pragma unroll
            for (int e = 0; e < 4; ++e) {
                const size_t r = (size_t)(row0 + wr * 64 + i * 16 + crow + e);
                C[r * 512 + col] = (u16)f2bfbits(acc[i][j][e] + bv);
            }
        }
    }
}

// ---------------- MFMA attention ----------------
// One block per (b,h,group), 384 threads = 6 waves, wave w owns q-rows 16w..16w+15.
// S = Q@K^T via MFMA (K from LDS, odd-chunk row stride -> conflict-free b128);
// in-register softmax (4x shfl_xor over the 16-lane col group); P -> LDS;
// O = P@V via MFMA with V stored transposed. Post-softmax mask = row scale on O.
__global__ __launch_bounds__(384)
void attn_mfma(const u16* __restrict__ q, const u16* __restrict__ kbuf,
               const u16* __restrict__ vbuf, const float* __restrict__ mask,
               u16* __restrict__ out, int time_axis)
{
    __shared__ __align__(16) u16 Ks[96][72];    // stride 144B = 9 chunks (odd)
    __shared__ __align__(16) u16 VT[64][104];   // V^T, stride 208B = 13 chunks
    __shared__ __align__(16) u16 Ps[96][104];
    const int g = blockIdx.x;
    const int h = g & 7;
    const int bs = g >> 3;
    const int b = bs / 96, st = bs % 96;
    const size_t base   = time_axis ? ((size_t)(b * 96 + st) * 96) : ((size_t)b * 9216 + st);
    const size_t stride = time_axis ? 1 : 96;
    const int tid = threadIdx.x;
    const int w = tid / 64, l = tid & 63;
    const int fr = l & 15, fk = (l >> 4) * 8;

    // ---- stage K (row-major) and V (transposed) ----
    for (int task = tid; task < 96 * 8; task += 384) {
        const int r = task >> 3, c = task & 7;
        *(uint4*)&Ks[r][c * 8] =
            *(const uint4*)(kbuf + (base + (size_t)r * stride) * 512 + h * 64 + c * 8);
    }
    for (int task = tid; task < 96 * 8; task += 384) {
        const int r = task >> 3, c = task & 7;
        uint4 dv = *(const uint4*)(vbuf + (base + (size_t)r * stride) * 512 + h * 64 + c * 8);
        const u16* e = (const u16*)&dv;
#pragma unroll
        for (int j = 0; j < 8; ++j) VT[c * 8 + j][r] = e[j];
    }
    // ---- Q fragments straight from global ----
    const u16* qp = q + (base + (size_t)(16 * w + fr) * stride) * 512 + h * 64;
    bf16x8 aq0 = *(const bf16x8*)(qp + fk);
    bf16x8 aq1 = *(const bf16x8*)(qp + 32 + fk);
    __syncthreads();

    // ---- S = Q @ K^T : 6 col-frags ----
    f32x4 s[6] = {};
#pragma unroll
    for (int fc = 0; fc < 6; ++fc) {
        bf16x8 b0 = *(const bf16x8*)&Ks[fc * 16 + fr][fk];
        bf16x8 b1 = *(const bf16x8*)&Ks[fc * 16 + fr][32 + fk];
        s[fc] = __builtin_amdgcn_mfma_f32_16x16x32_bf16(aq0, b0, s[fc], 0, 0, 0);
        s[fc] = __builtin_amdgcn_mfma_f32_16x16x32_bf16(aq1, b1, s[fc], 0, 0, 0);
    }
    // ---- softmax over 96 cols for the 4 q-rows this lane holds ----
    float mrow[4], lrow[4];
#pragma unroll
    for (int e = 0; e < 4; ++e) {
        float mx = s[0][e];
#pragma unroll
        for (int fc = 1; fc < 6; ++fc) mx = fmaxf(mx, s[fc][e]);
#pragma unroll
        for (int off = 1; off < 16; off <<= 1) mx = fmaxf(mx, __shfl_xor(mx, off));
        mrow[e] = mx * 0.125f;
        lrow[e] = 0.f;
    }
    const int e0 = (l >> 4) * 4;
#pragma unroll
    for (int fc = 0; fc < 6; ++fc) {
#pragma unroll
        for (int e = 0; e < 4; ++e) {
            const float p = __expf(fmaf(s[fc][e], 0.125f, -mrow[e]));
            lrow[e] += p;
            Ps[16 * w + e0 + e][fc * 16 + fr] = (u16)f2bfbits(p);
        }
    }
#pragma unroll
    for (int e = 0; e < 4; ++e)
#pragma unroll
        for (int off = 1; off < 16; off <<= 1) lrow[e] += __shfl_xor(lrow[e], off);

    __syncthreads();   // orders Ps writes (also covers cross-lane LDS visibility)

    // ---- O = P @ V ----
    f32x4 oacc[4] = {};
#pragma unroll
    for (int ks = 0; ks < 3; ++ks) {
        bf16x8 ap = *(const bf16x8*)&Ps[16 * w + fr][ks * 32 + fk];
#pragma unroll
        for (int j = 0; j < 4; ++j) {
            bf16x8 bv = *(const bf16x8*)&VT[j * 16 + fr][ks * 32 + fk];
            oacc[j] = __builtin_amdgcn_mfma_f32_16x16x32_bf16(ap, bv, oacc[j], 0, 0, 0);
        }
    }
    // ---- epilogue: scale by mask/lsum, write ----
    float mk[4];
#pragma unroll
    for (int e = 0; e < 4; ++e) {
        const size_t qrow = base + (size_t)(16 * w + e0 + e) * stride;
        mk[e] = mask[qrow] / lrow[e];
    }
#pragma unroll
    for (int j = 0; j < 4; ++j)
#pragma unroll
        for (int e = 0; e < 4; ++e) {
            const size_t qrow = base + (size_t)(16 * w + e0 + e) * stride;
            out[qrow * 512 + h * 64 + j * 16 + fr] = (u16)f2bfbits(oacc[j][e] * mk[e]);
        }
}

// ---------------- residual add + LayerNorm (one wave per row of 512) ----------------
template<typename TA, typename TB, typename TO>
__global__ __launch_bounds__(64)
void add_ln(const TA* __restrict__ a, const TB* __restrict__ bsrc,
            const float* __restrict__ g, const float* __restrict__ beta,
            TO* __restrict__ out)
{
    const size_t row = blockIdx.x;
    const int lane = threadIdx.x;
    float ya[8], yb[8], y[8];
    load8(a + row * D_ + lane * 8, ya);
    load8(bsrc + row * D_ + lane * 8, yb);
    float sum = 0.f, sq = 0.f;
#pragma unroll
    for (int i = 0; i < 8; ++i) { y[i] = ya[i] + yb[i]; sum += y[i]; sq += y[i] * y[i]; }
#pragma unroll
    for (int off = 32; off >= 1; off >>= 1) {
        sum += __shfl_xor(sum, off);
        sq  += __shfl_xor(sq, off);
    }
    const float mean = sum * (1.f / D_);
    const float var  = sq * (1.f / D_) - mean * mean;
    const float rstd = rsqrtf(var + EPS_);
    const float* gp = g + lane * 8;
    const float* bp = beta + lane * 8;
    float o[8];
#pragma unroll
    for (int i = 0; i < 8; ++i) o[i] = (y[i] - mean) * rstd * gp[i] + bp[i];
    store8(out + row * D_ + lane * 8, o);
}

extern "C" void kernel_launch(void* const* d_in, const int* in_sizes, int n_in,
                              void* d_out, int out_size, void* d_ws, size_t ws_size,
                              hipStream_t stream)
{
    const float* x     = (const float*)d_in[0];
    const float* mask  = (const float*)d_in[1];
    const float* t_w   = (const float*)d_in[2];
    const float* t_b   = (const float*)d_in[3];
    const float* s_w   = (const float*)d_in[4];
    const float* s_b   = (const float*)d_in[5];
    const float* fc_w1 = (const float*)d_in[6];
    const float* fc_b1 = (const float*)d_in[7];
    const float* fc_w2 = (const float*)d_in[8];
    const float* fc_b2 = (const float*)d_in[9];
    const float* ln1_g = (const float*)d_in[10];
    const float* ln1_b = (const float*)d_in[11];
    const float* ln2_g = (const float*)d_in[12];
    const float* ln2_b = (const float*)d_in[13];

    const size_t PG = (size_t)NROWS * 512;
    if (ws_size < PG * 3 * sizeof(u16)) return;
    u16* O0  = (u16*)d_out;
    u16* O1  = O0 + PG;
    u16* WS0 = (u16*)d_ws;
    u16* WS1 = WS0 + PG;
    u16* WS2 = WS1 + PG;

    const dim3 gblk(256);
    const dim3 ggrid(4, NROWS / 128);
    const dim3 qkvgrid(12, NROWS / 128);
    const dim3 t512(16, 16);

    // x -> bf16 (WS2)
    cvt_f32_bf16<<<dim3((unsigned)(PG / 2048)), gblk, 0, stream>>>(x, WS2);
    // t_w[0..2] -> WT bf16 in O1 (contiguous 1536 x 512)
    for (int i = 0; i < 3; ++i)
        tconv<<<t512, gblk, 0, stream>>>(t_w + (size_t)i * DD_, O1 + (size_t)i * DD_, 512, 512);
    // time QKV (fused): q->O0, k->WS0, v->WS1
    gemm_qkv<<<qkvgrid, gblk, 0, stream>>>(WS2, O1, t_b, O0, WS0, WS1);
    // t_w3, s_w0..3 -> WT bf16 in WS2 (xb dead)
    tconv<<<t512, gblk, 0, stream>>>(t_w + (size_t)3 * DD_, WS2, 512, 512);
    for (int i = 0; i < 4; ++i)
        tconv<<<t512, gblk, 0, stream>>>(s_w + (size_t)i * DD_, WS2 + (size_t)(1 + i) * DD_, 512, 512);
    attn_mfma<<<dim3(B_ * H_ * 96), dim3(384), 0, stream>>>(O0, WS0, WS1, mask, O0, 1);
    gemm_mfma<0, false><<<ggrid, gblk, 0, stream>>>(O0, WS2, t_b + 3 * 512, O1, 512);      // tt
    // space QKV (fused, WT pages 1..3 of WS2 contiguous)
    gemm_qkv<<<qkvgrid, gblk, 0, stream>>>(O1, WS2 + (size_t)DD_, s_b, O0, WS0, WS1);
    attn_mfma<<<dim3(B_ * H_ * 96), dim3(384), 0, stream>>>(O0, WS0, WS1, mask, O0, 0);
    gemm_mfma<0, false><<<ggrid, gblk, 0, stream>>>(O0, WS2 + (size_t)4 * DD_, s_b + 3 * 512, O1, 512); // ss
    // LN1: x1 = LN(x + ss) -> WS0
    add_ln<float, u16, u16><<<dim3(NROWS), dim3(64), 0, stream>>>(x, O1, ln1_g, ln1_b, WS0);
    // fc WTs -> O0 (att dead)
    u16* WT1 = O0;
    u16* WT2 = O0 + (size_t)2048 * 512;
    tconv<<<dim3(64, 16), gblk, 0, stream>>>(fc_w1, WT1, 512, 2048);
    tconv<<<dim3(16, 64), gblk, 0, stream>>>(fc_w2, WT2, 2048, 512);
    // FFN chunked over FF in 4 x 512
    for (int c = 0; c < 4; ++c) {
        gemm_mfma<1, false><<<ggrid, gblk, 0, stream>>>(
            WS0, WT1 + (size_t)c * 512 * 512, fc_b1 + c * 512, WS1, 512);       // h = leaky
        if (c == 0)
            gemm_mfma<0, false><<<ggrid, gblk, 0, stream>>>(
                WS1, WT2 + (size_t)c * 512, fc_b2, WS2, 2048);
        else
            gemm_mfma<0, true><<<ggrid, gblk, 0, stream>>>(
                WS1, WT2 + (size_t)c * 512, nullptr, WS2, 2048);
    }
    // LN2: out = LN(x1 + ff) -> fp32 d_out (reads WS0/WS2 only)
    add_ln<u16, u16, float><<<dim3(NROWS), dim3(64), 0, stream>>>(
        WS0, WS2, ln2_g, ln2_b, (float*)d_out);
}

// Round 5
// 651.071 us; speedup vs baseline: 7.0943x; 1.2087x over previous
//
#include <hip/hip_runtime.h>
#include <hip/hip_bf16.h>

#define B_ 4
#define S_ 96
#define T_ 96
#define D_ 512
#define H_ 8
#define FF_ 2048
#define NROWS (B_*S_*T_)   // 36864
#define EPS_ 1e-5f
#define NEG_ 0.01f
#define DD_ (512*512)

typedef unsigned short u16;   // bf16 bits
typedef __attribute__((ext_vector_type(8))) short bf16x8;
typedef __attribute__((ext_vector_type(4))) float f32x4;
typedef __attribute__((address_space(1))) const unsigned glb_u32;
typedef __attribute__((address_space(3))) unsigned lds_u32;

__device__ __forceinline__ float bf(u16 u) { return __uint_as_float(((unsigned)u) << 16); }
__device__ __forceinline__ unsigned f2bfbits(float f) {
    unsigned x = __float_as_uint(f);
    return (x + 0x7fffu + ((x >> 16) & 1u)) >> 16;   // RNE
}
__device__ __forceinline__ float blo(unsigned v) { return __uint_as_float(v << 16); }
__device__ __forceinline__ float bhi(unsigned v) { return __uint_as_float(v & 0xffff0000u); }

__device__ __forceinline__ float cvt_ld(float x) { return x; }
__device__ __forceinline__ float cvt_ld(u16 x)  { return bf(x); }
__device__ __forceinline__ void cvt_st(float* p, float v) { *p = v; }
__device__ __forceinline__ void cvt_st(u16* p, float v)   { *p = (u16)f2bfbits(v); }

__device__ __forceinline__ void load8(const float* p, float* y) {
    float4 a = *(const float4*)p, b = *(const float4*)(p + 4);
    y[0]=a.x; y[1]=a.y; y[2]=a.z; y[3]=a.w; y[4]=b.x; y[5]=b.y; y[6]=b.z; y[7]=b.w;
}
__device__ __forceinline__ void load8(const u16* p, float* y) {
    uint4 u = *(const uint4*)p;
    y[0]=blo(u.x); y[1]=bhi(u.x); y[2]=blo(u.y); y[3]=bhi(u.y);
    y[4]=blo(u.z); y[5]=bhi(u.z); y[6]=blo(u.w); y[7]=bhi(u.w);
}
__device__ __forceinline__ void store8(float* p, const float* y) {
    *(float4*)p       = make_float4(y[0], y[1], y[2], y[3]);
    *(float4*)(p + 4) = make_float4(y[4], y[5], y[6], y[7]);
}
__device__ __forceinline__ void store8(u16* p, const float* y) {
    uint4 u;
    u.x = f2bfbits(y[0]) | (f2bfbits(y[1]) << 16);
    u.y = f2bfbits(y[2]) | (f2bfbits(y[3]) << 16);
    u.z = f2bfbits(y[4]) | (f2bfbits(y[5]) << 16);
    u.w = f2bfbits(y[6]) | (f2bfbits(y[7]) << 16);
    *(uint4*)p = u;
}

// ---------------- fp32 -> bf16 elementwise ----------------
__global__ __launch_bounds__(256)
void cvt_f32_bf16(const float* __restrict__ in, u16* __restrict__ out)
{
    const size_t i = ((size_t)blockIdx.x * 256 + threadIdx.x) * 8;
    float y[8];
    load8(in + i, y);
    store8(out + i, y);
}

// ---------------- transpose + convert: out[C x R] bf16 = in[R x C]^T ----------------
__global__ __launch_bounds__(256)
void tconv(const float* __restrict__ in, u16* __restrict__ out, int R, int C)
{
    __shared__ float t[32][33];
    const int c0 = blockIdx.x * 32, r0 = blockIdx.y * 32;
    const int tr = threadIdx.x >> 3, c4 = (threadIdx.x & 7) * 4;
    float4 v = *(const float4*)(in + (size_t)(r0 + tr) * C + c0 + c4);
    t[tr][c4] = v.x; t[tr][c4 + 1] = v.y; t[tr][c4 + 2] = v.z; t[tr][c4 + 3] = v.w;
    __syncthreads();
    const int oc = tr, r4 = c4;
    ushort4 u;
    u.x = (u16)f2bfbits(t[r4 + 0][oc]); u.y = (u16)f2bfbits(t[r4 + 1][oc]);
    u.z = (u16)f2bfbits(t[r4 + 2][oc]); u.w = (u16)f2bfbits(t[r4 + 3][oc]);
    *(ushort4*)(out + (size_t)(c0 + oc) * R + r0 + r4) = u;
}

// ================= MFMA GEMM v2 =================
// C = act(A @ WT^T [+ bias | + C_old]).  A (NROWS x K) lda; WT (N x K) ldwt;
// C (NROWS x ldc) TC = u16|float.  128x128 tile, BK=64, double-buffered LDS,
// one barrier per K-step, XCD-chunked grid swizzle, XOR bank-deswizzle.
// LDS tiles [line][64]: linear gload_lds dest; SOURCE k-chunk pre-swizzled
// (l&7)^(l>>3); reads XOR chunk with row&7  (both-sides rule).
template<int ACT, bool ACC, typename TC>
__global__ __launch_bounds__(256)
void gemm2(const u16* __restrict__ A, const u16* __restrict__ WT,
           const float* __restrict__ bias, TC* __restrict__ C,
           int K, int lda, int ldwt, int ldc)
{
    __shared__ u16 As[2][128 * 64];
    __shared__ u16 Bs[2][128 * 64];
    const int tid = threadIdx.x;
    const int w = tid >> 6, l = tid & 63;
    const int wr = w >> 1, wc = w & 1;
    // T1: bijective XCD-chunked swizzle (grid count always % 8 == 0)
    const unsigned gx = gridDim.x;
    const unsigned n = gx * gridDim.y;
    unsigned f = blockIdx.y * gx + blockIdx.x;
    f = (f & 7) * (n >> 3) + (f >> 3);
    const int row0 = (int)(f / gx) * 128, col0 = (int)(f % gx) * 128;

    const int lrow = l >> 3;
    const int swz8 = (((l & 7) ^ lrow) << 3);   // pre-swizzled source chunk
    const int fr16 = l & 15;
    const int kq = l >> 4;

    f32x4 acc[4][4] = {};

    auto stage = [&](int buf, int kt) {
#pragma unroll
        for (int j = 0; j < 4; ++j) {
            const int line = w * 32 + j * 8;
            const u16* asrc = A  + (size_t)(row0 + line + lrow) * lda  + kt + swz8;
            const u16* bsrc = WT + (size_t)(col0 + line + lrow) * ldwt + kt + swz8;
            __builtin_amdgcn_global_load_lds((glb_u32*)asrc, (lds_u32*)&As[buf][line * 64], 16, 0, 0);
            __builtin_amdgcn_global_load_lds((glb_u32*)bsrc, (lds_u32*)&Bs[buf][line * 64], 16, 0, 0);
        }
    };

    stage(0, 0);
    __syncthreads();
    for (int kt = 0; kt < K; kt += 64) {
        const int cur = (kt >> 6) & 1;
        if (kt + 64 < K) stage(cur ^ 1, kt + 64);   // prefetch overlaps compute
#pragma unroll
        for (int kk = 0; kk < 2; ++kk) {
            const int sw = ((((kk << 2) | kq)) ^ (fr16 & 7)) << 3;  // de-swizzled read
            bf16x8 af[4], bfr[4];
#pragma unroll
            for (int i = 0; i < 4; ++i)
                af[i] = *(bf16x8*)&As[cur][(wr * 64 + i * 16 + fr16) * 64 + sw];
#pragma unroll
            for (int j = 0; j < 4; ++j)
                bfr[j] = *(bf16x8*)&Bs[cur][(wc * 64 + j * 16 + fr16) * 64 + sw];
#pragma unroll
            for (int i = 0; i < 4; ++i)
#pragma unroll
                for (int j = 0; j < 4; ++j)
                    acc[i][j] = __builtin_amdgcn_mfma_f32_16x16x32_bf16(af[i], bfr[j], acc[i][j], 0, 0, 0);
        }
        __syncthreads();
    }
    const int crow = kq * 4;
#pragma unroll
    for (int i = 0; i < 4; ++i)
#pragma unroll
        for (int j = 0; j < 4; ++j) {
            const int col = col0 + wc * 64 + j * 16 + fr16;
            const float bv = ACC ? 0.f : bias[col];
#pragma unroll
            for (int e = 0; e < 4; ++e) {
                const size_t r = (size_t)(row0 + wr * 64 + i * 16 + crow + e);
                TC* cp = &C[r * (size_t)ldc + col];
                float v = acc[i][j][e] + bv;
                if (ACC) v += cvt_ld(*cp);
                if (ACT == 1) v = (v >= 0.f) ? v : NEG_ * v;
                cvt_st(cp, v);
            }
        }
}

// ---------------- fused QKV GEMM (same improvements), WT (1536 x 512) ----------------
__global__ __launch_bounds__(256)
void gemm_qkv(const u16* __restrict__ A, const u16* __restrict__ WT,
              const float* __restrict__ bias,
              u16* __restrict__ c0, u16* __restrict__ c1, u16* __restrict__ c2)
{
    __shared__ u16 As[2][128 * 64];
    __shared__ u16 Bs[2][128 * 64];
    const int tid = threadIdx.x;
    const int w = tid >> 6, l = tid & 63;
    const int wr = w >> 1, wc = w & 1;
    const unsigned gx = gridDim.x;            // 12
    const unsigned n = gx * gridDim.y;
    unsigned f = blockIdx.y * gx + blockIdx.x;
    f = (f & 7) * (n >> 3) + (f >> 3);
    const int row0 = (int)(f / gx) * 128;
    const int bxs = (int)(f % gx);
    const int wtrow0 = bxs * 128;
    const int page = bxs >> 2;
    const int colp0 = (bxs & 3) * 128;
    u16* C = (page == 0) ? c0 : (page == 1) ? c1 : c2;

    const int lrow = l >> 3;
    const int swz8 = (((l & 7) ^ lrow) << 3);
    const int fr16 = l & 15;
    const int kq = l >> 4;

    f32x4 acc[4][4] = {};

    auto stage = [&](int buf, int kt) {
#pragma unroll
        for (int j = 0; j < 4; ++j) {
            const int line = w * 32 + j * 8;
            const u16* asrc = A  + (size_t)(row0 + line + lrow) * 512 + kt + swz8;
            const u16* bsrc = WT + (size_t)(wtrow0 + line + lrow) * 512 + kt + swz8;
            __builtin_amdgcn_global_load_lds((glb_u32*)asrc, (lds_u32*)&As[buf][line * 64], 16, 0, 0);
            __builtin_amdgcn_global_load_lds((glb_u32*)bsrc, (lds_u32*)&Bs[buf][line * 64], 16, 0, 0);
        }
    };

    stage(0, 0);
    __syncthreads();
    for (int kt = 0; kt < 512; kt += 64) {
        const int cur = (kt >> 6) & 1;
        if (kt + 64 < 512) stage(cur ^ 1, kt + 64);
#pragma unroll
        for (int kk = 0; kk < 2; ++kk) {
            const int sw = ((((kk << 2) | kq)) ^ (fr16 & 7)) << 3;
            bf16x8 af[4], bfr[4];
#pragma unroll
            for (int i = 0; i < 4; ++i)
                af[i] = *(bf16x8*)&As[cur][(wr * 64 + i * 16 + fr16) * 64 + sw];
#pragma unroll
            for (int j = 0; j < 4; ++j)
                bfr[j] = *(bf16x8*)&Bs[cur][(wc * 64 + j * 16 + fr16) * 64 + sw];
#pragma unroll
            for (int i = 0; i < 4; ++i)
#pragma unroll
                for (int j = 0; j < 4; ++j)
                    acc[i][j] = __builtin_amdgcn_mfma_f32_16x16x32_bf16(af[i], bfr[j], acc[i][j], 0, 0, 0);
        }
        __syncthreads();
    }
    const int crow = kq * 4;
#pragma unroll
    for (int i = 0; i < 4; ++i)
#pragma unroll
        for (int j = 0; j < 4; ++j) {
            const int col = colp0 + wc * 64 + j * 16 + fr16;
            const float bv = bias[wtrow0 + wc * 64 + j * 16 + fr16];
#pragma unroll
            for (int e = 0; e < 4; ++e) {
                const size_t r = (size_t)(row0 + wr * 64 + i * 16 + crow + e);
                C[r * 512 + col] = (u16)f2bfbits(acc[i][j][e] + bv);
            }
        }
}

// ---------------- MFMA attention (round-4, verified) ----------------
__global__ __launch_bounds__(384)
void attn_mfma(const u16* __restrict__ q, const u16* __restrict__ kbuf,
               const u16* __restrict__ vbuf, const float* __restrict__ mask,
               u16* __restrict__ out, int time_axis)
{
    __shared__ __align__(16) u16 Ks[96][72];
    __shared__ __align__(16) u16 VT[64][104];
    __shared__ __align__(16) u16 Ps[96][104];
    const int g = blockIdx.x;
    const int h = g & 7;
    const int bs = g >> 3;
    const int b = bs / 96, st = bs % 96;
    const size_t base   = time_axis ? ((size_t)(b * 96 + st) * 96) : ((size_t)b * 9216 + st);
    const size_t stride = time_axis ? 1 : 96;
    const int tid = threadIdx.x;
    const int w = tid / 64, l = tid & 63;
    const int fr = l & 15, fk = (l >> 4) * 8;

    for (int task = tid; task < 96 * 8; task += 384) {
        const int r = task >> 3, c = task & 7;
        *(uint4*)&Ks[r][c * 8] =
            *(const uint4*)(kbuf + (base + (size_t)r * stride) * 512 + h * 64 + c * 8);
    }
    for (int task = tid; task < 96 * 8; task += 384) {
        const int r = task >> 3, c = task & 7;
        uint4 dv = *(const uint4*)(vbuf + (base + (size_t)r * stride) * 512 + h * 64 + c * 8);
        const u16* e = (const u16*)&dv;
#pragma unroll
        for (int j = 0; j < 8; ++j) VT[c * 8 + j][r] = e[j];
    }
    const u16* qp = q + (base + (size_t)(16 * w + fr) * stride) * 512 + h * 64;
    bf16x8 aq0 = *(const bf16x8*)(qp + fk);
    bf16x8 aq1 = *(const bf16x8*)(qp + 32 + fk);
    __syncthreads();

    f32x4 s[6] = {};
#pragma unroll
    for (int fc = 0; fc < 6; ++fc) {
        bf16x8 b0 = *(const bf16x8*)&Ks[fc * 16 + fr][fk];
        bf16x8 b1 = *(const bf16x8*)&Ks[fc * 16 + fr][32 + fk];
        s[fc] = __builtin_amdgcn_mfma_f32_16x16x32_bf16(aq0, b0, s[fc], 0, 0, 0);
        s[fc] = __builtin_amdgcn_mfma_f32_16x16x32_bf16(aq1, b1, s[fc], 0, 0, 0);
    }
    float mrow[4], lrow[4];
#pragma unroll
    for (int e = 0; e < 4; ++e) {
        float mx = s[0][e];
#pragma unroll
        for (int fc = 1; fc < 6; ++fc) mx = fmaxf(mx, s[fc][e]);
#pragma unroll
        for (int off = 1; off < 16; off <<= 1) mx = fmaxf(mx, __shfl_xor(mx, off));
        mrow[e] = mx * 0.125f;
        lrow[e] = 0.f;
    }
    const int e0 = (l >> 4) * 4;
#pragma unroll
    for (int fc = 0; fc < 6; ++fc) {
#pragma unroll
        for (int e = 0; e < 4; ++e) {
            const float p = __expf(fmaf(s[fc][e], 0.125f, -mrow[e]));
            lrow[e] += p;
            Ps[16 * w + e0 + e][fc * 16 + fr] = (u16)f2bfbits(p);
        }
    }
#pragma unroll
    for (int e = 0; e < 4; ++e)
#pragma unroll
        for (int off = 1; off < 16; off <<= 1) lrow[e] += __shfl_xor(lrow[e], off);

    __syncthreads();

    f32x4 oacc[4] = {};
#pragma unroll
    for (int ks = 0; ks < 3; ++ks) {
        bf16x8 ap = *(const bf16x8*)&Ps[16 * w + fr][ks * 32 + fk];
#pragma unroll
        for (int j = 0; j < 4; ++j) {
            bf16x8 bv = *(const bf16x8*)&VT[j * 16 + fr][ks * 32 + fk];
            oacc[j] = __builtin_amdgcn_mfma_f32_16x16x32_bf16(ap, bv, oacc[j], 0, 0, 0);
        }
    }
    float mk[4];
#pragma unroll
    for (int e = 0; e < 4; ++e) {
        const size_t qrow = base + (size_t)(16 * w + e0 + e) * stride;
        mk[e] = mask[qrow] / lrow[e];
    }
#pragma unroll
    for (int j = 0; j < 4; ++j)
#pragma unroll
        for (int e = 0; e < 4; ++e) {
            const size_t qrow = base + (size_t)(16 * w + e0 + e) * stride;
            out[qrow * 512 + h * 64 + j * 16 + fr] = (u16)f2bfbits(oacc[j][e] * mk[e]);
        }
}

// ---------------- residual add + LayerNorm (one wave per row of 512) ----------------
template<typename TA, typename TB, typename TO>
__global__ __launch_bounds__(64)
void add_ln(const TA* __restrict__ a, const TB* __restrict__ bsrc,
            const float* __restrict__ g, const float* __restrict__ beta,
            TO* __restrict__ out)
{
    const size_t row = blockIdx.x;
    const int lane = threadIdx.x;
    float ya[8], yb[8], y[8];
    load8(a + row * D_ + lane * 8, ya);
    load8(bsrc + row * D_ + lane * 8, yb);
    float sum = 0.f, sq = 0.f;
#pragma unroll
    for (int i = 0; i < 8; ++i) { y[i] = ya[i] + yb[i]; sum += y[i]; sq += y[i] * y[i]; }
#pragma unroll
    for (int off = 32; off >= 1; off >>= 1) {
        sum += __shfl_xor(sum, off);
        sq  += __shfl_xor(sq, off);
    }
    const float mean = sum * (1.f / D_);
    const float var  = sq * (1.f / D_) - mean * mean;
    const float rstd = rsqrtf(var + EPS_);
    const float* gp = g + lane * 8;
    const float* bp = beta + lane * 8;
    float o[8];
#pragma unroll
    for (int i = 0; i < 8; ++i) o[i] = (y[i] - mean) * rstd * gp[i] + bp[i];
    store8(out + row * D_ + lane * 8, o);
}

extern "C" void kernel_launch(void* const* d_in, const int* in_sizes, int n_in,
                              void* d_out, int out_size, void* d_ws, size_t ws_size,
                              hipStream_t stream)
{
    const float* x     = (const float*)d_in[0];
    const float* mask  = (const float*)d_in[1];
    const float* t_w   = (const float*)d_in[2];
    const float* t_b   = (const float*)d_in[3];
    const float* s_w   = (const float*)d_in[4];
    const float* s_b   = (const float*)d_in[5];
    const float* fc_w1 = (const float*)d_in[6];
    const float* fc_b1 = (const float*)d_in[7];
    const float* fc_w2 = (const float*)d_in[8];
    const float* fc_b2 = (const float*)d_in[9];
    const float* ln1_g = (const float*)d_in[10];
    const float* ln1_b = (const float*)d_in[11];
    const float* ln2_g = (const float*)d_in[12];
    const float* ln2_b = (const float*)d_in[13];

    const size_t PG = (size_t)NROWS * 512;
    if (ws_size < PG * 3 * sizeof(u16)) return;
    u16* O0  = (u16*)d_out;
    u16* O1  = O0 + PG;
    u16* WS0 = (u16*)d_ws;
    u16* WS1 = WS0 + PG;
    u16* WS2 = WS1 + PG;
    // fat FFN path needs a 4.2 MB fc-weight corner beyond the 3 pages
    const size_t WTC = (size_t)2048 * 512 * 2;   // elements for WT1f+WT2f
    const bool FAT = ws_size >= PG * 3 * sizeof(u16) + WTC * sizeof(u16);

    const dim3 gblk(256);
    const dim3 g512(4, NROWS / 128);
    const dim3 g1024(8, NROWS / 128);
    const dim3 qkvgrid(12, NROWS / 128);
    const dim3 t512(16, 16);

    // x -> bf16 (WS2)
    cvt_f32_bf16<<<dim3((unsigned)(PG / 2048)), gblk, 0, stream>>>(x, WS2);
    // t_w[0..2] -> WT bf16 in O1 (contiguous 1536 x 512)
    for (int i = 0; i < 3; ++i)
        tconv<<<t512, gblk, 0, stream>>>(t_w + (size_t)i * DD_, O1 + (size_t)i * DD_, 512, 512);
    // time QKV: q->O0, k->WS0, v->WS1
    gemm_qkv<<<qkvgrid, gblk, 0, stream>>>(WS2, O1, t_b, O0, WS0, WS1);
    // t_w3, s_w0..3 -> WT bf16 in WS2 (xb dead)
    tconv<<<t512, gblk, 0, stream>>>(t_w + (size_t)3 * DD_, WS2, 512, 512);
    for (int i = 0; i < 4; ++i)
        tconv<<<t512, gblk, 0, stream>>>(s_w + (size_t)i * DD_, WS2 + (size_t)(1 + i) * DD_, 512, 512);
    attn_mfma<<<dim3(B_ * H_ * 96), dim3(384), 0, stream>>>(O0, WS0, WS1, mask, O0, 1);
    gemm2<0, false, u16><<<g512, gblk, 0, stream>>>(O0, WS2, t_b + 3 * 512, O1, 512, 512, 512, 512);  // tt
    // space QKV
    gemm_qkv<<<qkvgrid, gblk, 0, stream>>>(O1, WS2 + (size_t)DD_, s_b, O0, WS0, WS1);
    attn_mfma<<<dim3(B_ * H_ * 96), dim3(384), 0, stream>>>(O0, WS0, WS1, mask, O0, 0);
    gemm2<0, false, u16><<<g512, gblk, 0, stream>>>(O0, WS2 + (size_t)4 * DD_, s_b + 3 * 512, O1, 512, 512, 512, 512); // ss
    // LN1: x1 = LN(x + ss) -> WS0
    add_ln<float, u16, u16><<<dim3(NROWS), dim3(64), 0, stream>>>(x, O1, ln1_g, ln1_b, WS0);

    if (FAT) {
        // fc WTs -> ws tail (survives d_out clobber)
        u16* WT1f = WS0 + 3 * PG;
        u16* WT2f = WT1f + (size_t)2048 * 512;
        tconv<<<dim3(64, 16), gblk, 0, stream>>>(fc_w1, WT1f, 512, 2048);
        tconv<<<dim3(16, 64), gblk, 0, stream>>>(fc_w2, WT2f, 2048, 512);
        float* ff = (float*)d_out;
        // chunk 0: h (N=1024) -> WS1:WS2 contiguous; ff (K=1024) -> fp32 d_out
        gemm2<1, false, u16><<<g1024, gblk, 0, stream>>>(WS0, WT1f, fc_b1, WS1, 512, 512, 512, 1024);
        gemm2<0, false, float><<<g512, gblk, 0, stream>>>(WS1, WT2f, fc_b2, ff, 1024, 1024, 2048, 512);
        // chunk 1
        gemm2<1, false, u16><<<g1024, gblk, 0, stream>>>(WS0, WT1f + (size_t)1024 * 512, fc_b1 + 1024, WS1, 512, 512, 512, 1024);
        gemm2<0, true, float><<<g512, gblk, 0, stream>>>(WS1, WT2f + 1024, nullptr, ff, 1024, 1024, 2048, 512);
        // LN2 in-place on d_out (per-row)
        add_ln<u16, float, float><<<dim3(NROWS), dim3(64), 0, stream>>>(WS0, ff, ln2_g, ln2_b, ff);
    } else {
        // small path: fc WTs -> O0 (att dead), h 512-chunks -> WS1, ff bf16 -> WS2
        u16* WT1 = O0;
        u16* WT2 = O0 + (size_t)2048 * 512;
        tconv<<<dim3(64, 16), gblk, 0, stream>>>(fc_w1, WT1, 512, 2048);
        tconv<<<dim3(16, 64), gblk, 0, stream>>>(fc_w2, WT2, 2048, 512);
        for (int c = 0; c < 4; ++c) {
            gemm2<1, false, u16><<<g512, gblk, 0, stream>>>(
                WS0, WT1 + (size_t)c * 512 * 512, fc_b1 + c * 512, WS1, 512, 512, 512, 512);
            if (c == 0)
                gemm2<0, false, u16><<<g512, gblk, 0, stream>>>(
                    WS1, WT2 + (size_t)c * 512, fc_b2, WS2, 512, 512, 2048, 512);
            else
                gemm2<0, true, u16><<<g512, gblk, 0, stream>>>(
                    WS1, WT2 + (size_t)c * 512, nullptr, WS2, 512, 512, 2048, 512);
        }
        add_ln<u16, u16, float><<<dim3(NROWS), dim3(64), 0, stream>>>(
            WS0, WS2, ln2_g, ln2_b, (float*)d_out);
    }
}

// Round 7
// 635.650 us; speedup vs baseline: 7.2664x; 1.0243x over previous
//
#include <hip/hip_runtime.h>
#include <hip/hip_bf16.h>

#define B_ 4
#define S_ 96
#define T_ 96
#define D_ 512
#define H_ 8
#define FF_ 2048
#define NROWS (B_*S_*T_)   // 36864
#define EPS_ 1e-5f
#define NEG_ 0.01f
#define DD_ (512*512)

typedef unsigned short u16;   // bf16 bits
typedef __attribute__((ext_vector_type(8))) short bf16x8;
typedef __attribute__((ext_vector_type(4))) float f32x4;
typedef __attribute__((address_space(1))) const unsigned glb_u32;
typedef __attribute__((address_space(3))) unsigned lds_u32;

__device__ __forceinline__ float bf(u16 u) { return __uint_as_float(((unsigned)u) << 16); }
__device__ __forceinline__ unsigned f2bfbits(float f) {
    unsigned x = __float_as_uint(f);
    return (x + 0x7fffu + ((x >> 16) & 1u)) >> 16;   // RNE
}
__device__ __forceinline__ float blo(unsigned v) { return __uint_as_float(v << 16); }
__device__ __forceinline__ float bhi(unsigned v) { return __uint_as_float(v & 0xffff0000u); }

__device__ __forceinline__ float cvt_ld(float x) { return x; }
__device__ __forceinline__ float cvt_ld(u16 x)  { return bf(x); }
__device__ __forceinline__ void cvt_st(float* p, float v) { *p = v; }
__device__ __forceinline__ void cvt_st(u16* p, float v)   { *p = (u16)f2bfbits(v); }

__device__ __forceinline__ void load8(const float* p, float* y) {
    float4 a = *(const float4*)p, b = *(const float4*)(p + 4);
    y[0]=a.x; y[1]=a.y; y[2]=a.z; y[3]=a.w; y[4]=b.x; y[5]=b.y; y[6]=b.z; y[7]=b.w;
}
__device__ __forceinline__ void load8(const u16* p, float* y) {
    uint4 u = *(const uint4*)p;
    y[0]=blo(u.x); y[1]=bhi(u.x); y[2]=blo(u.y); y[3]=bhi(u.y);
    y[4]=blo(u.z); y[5]=bhi(u.z); y[6]=blo(u.w); y[7]=bhi(u.w);
}
__device__ __forceinline__ void store8(float* p, const float* y) {
    *(float4*)p       = make_float4(y[0], y[1], y[2], y[3]);
    *(float4*)(p + 4) = make_float4(y[4], y[5], y[6], y[7]);
}
__device__ __forceinline__ void store8(u16* p, const float* y) {
    uint4 u;
    u.x = f2bfbits(y[0]) | (f2bfbits(y[1]) << 16);
    u.y = f2bfbits(y[2]) | (f2bfbits(y[3]) << 16);
    u.z = f2bfbits(y[4]) | (f2bfbits(y[5]) << 16);
    u.w = f2bfbits(y[6]) | (f2bfbits(y[7]) << 16);
    *(uint4*)p = u;
}

// ---------------- fp32 -> bf16 elementwise ----------------
__global__ __launch_bounds__(256)
void cvt_f32_bf16(const float* __restrict__ in, u16* __restrict__ out)
{
    const size_t i = ((size_t)blockIdx.x * 256 + threadIdx.x) * 8;
    float y[8];
    load8(in + i, y);
    store8(out + i, y);
}

// ---------------- transpose + convert: out[C x R] bf16 = in[R x C]^T ----------------
__global__ __launch_bounds__(256)
void tconv(const float* __restrict__ in, u16* __restrict__ out, int R, int C)
{
    __shared__ float t[32][33];
    const int c0 = blockIdx.x * 32, r0 = blockIdx.y * 32;
    const int tr = threadIdx.x >> 3, c4 = (threadIdx.x & 7) * 4;
    float4 v = *(const float4*)(in + (size_t)(r0 + tr) * C + c0 + c4);
    t[tr][c4] = v.x; t[tr][c4 + 1] = v.y; t[tr][c4 + 2] = v.z; t[tr][c4 + 3] = v.w;
    __syncthreads();
    const int oc = tr, r4 = c4;
    ushort4 u;
    u.x = (u16)f2bfbits(t[r4 + 0][oc]); u.y = (u16)f2bfbits(t[r4 + 1][oc]);
    u.z = (u16)f2bfbits(t[r4 + 2][oc]); u.w = (u16)f2bfbits(t[r4 + 3][oc]);
    *(ushort4*)(out + (size_t)(c0 + oc) * R + r0 + r4) = u;
}

// ======== shared GEMM machinery: 128x128 tile, BK=64, single-buffer 32 KB,
// XOR bank-deswizzle (both-sides), XCD-chunked grid swizzle ========
#define GEMM_PRE()                                                              \
    const int tid = threadIdx.x;                                                \
    const int w = tid >> 6, l = tid & 63;                                       \
    const int wr = w >> 1, wc = w & 1;                                          \
    const unsigned gx = gridDim.x;                                              \
    const unsigned nwg = gx * gridDim.y;                                        \
    unsigned f = blockIdx.y * gx + blockIdx.x;                                  \
    f = (f & 7) * (nwg >> 3) + (f >> 3);                                        \
    const int lrow = l >> 3;                                                    \
    const int swz8 = (((l & 7) ^ lrow) << 3);                                   \
    const int fr16 = l & 15;                                                    \
    const int kq = l >> 4;

#define GEMM_COMPUTE()                                                          \
    _Pragma("unroll")                                                           \
    for (int kk = 0; kk < 2; ++kk) {                                            \
        const int sw = ((((kk << 2) | kq)) ^ (fr16 & 7)) << 3;                  \
        bf16x8 af[4], bfr[4];                                                   \
        _Pragma("unroll")                                                       \
        for (int i = 0; i < 4; ++i)                                             \
            af[i] = *(bf16x8*)&As[(wr * 64 + i * 16 + fr16) * 64 + sw];         \
        _Pragma("unroll")                                                       \
        for (int j = 0; j < 4; ++j)                                             \
            bfr[j] = *(bf16x8*)&Bs[(wc * 64 + j * 16 + fr16) * 64 + sw];        \
        _Pragma("unroll")                                                       \
        for (int i = 0; i < 4; ++i)                                             \
            _Pragma("unroll")                                                   \
            for (int j = 0; j < 4; ++j)                                         \
                acc[i][j] = __builtin_amdgcn_mfma_f32_16x16x32_bf16(af[i], bfr[j], acc[i][j], 0, 0, 0); \
    }

// ---------------- generic GEMM: C = act(A @ WT^T + bias | +C) ----------------
template<int ACT, bool ACC, typename TC>
__global__ __launch_bounds__(256)
void gemm2(const u16* __restrict__ A, const u16* __restrict__ WT,
           const float* __restrict__ bias, TC* __restrict__ C,
           int K, int lda, int ldwt, int ldc)
{
    __shared__ u16 As[128 * 64];
    __shared__ u16 Bs[128 * 64];
    GEMM_PRE();
    const int row0 = (int)(f / gx) * 128, col0 = (int)(f % gx) * 128;
    f32x4 acc[4][4] = {};

    for (int kt = 0; kt < K; kt += 64) {
#pragma unroll
        for (int j = 0; j < 4; ++j) {
            const int line = w * 32 + j * 8;
            const u16* asrc = A  + (size_t)(row0 + line + lrow) * lda  + kt + swz8;
            const u16* bsrc = WT + (size_t)(col0 + line + lrow) * ldwt + kt + swz8;
            __builtin_amdgcn_global_load_lds((glb_u32*)asrc, (lds_u32*)&As[line * 64], 16, 0, 0);
            __builtin_amdgcn_global_load_lds((glb_u32*)bsrc, (lds_u32*)&Bs[line * 64], 16, 0, 0);
        }
        __syncthreads();
        GEMM_COMPUTE();
        __syncthreads();
    }
    const int crow = kq * 4;
#pragma unroll
    for (int i = 0; i < 4; ++i)
#pragma unroll
        for (int j = 0; j < 4; ++j) {
            const int col = col0 + wc * 64 + j * 16 + fr16;
            const float bv = ACC ? 0.f : bias[col];
#pragma unroll
            for (int e = 0; e < 4; ++e) {
                const size_t r = (size_t)(row0 + wr * 64 + i * 16 + crow + e);
                TC* cp = &C[r * (size_t)ldc + col];
                float v = acc[i][j][e] + bv;
                if (ACC) v += cvt_ld(*cp);
                if (ACT == 1) v = (v >= 0.f) ? v : NEG_ * v;
                cvt_st(cp, v);
            }
        }
}

// ---------------- fused QKV: WT (1536 x 512), 3 output pages ----------------
__global__ __launch_bounds__(256)
void gemm_qkv(const u16* __restrict__ A, const u16* __restrict__ WT,
              const float* __restrict__ bias,
              u16* __restrict__ c0, u16* __restrict__ c1, u16* __restrict__ c2)
{
    __shared__ u16 As[128 * 64];
    __shared__ u16 Bs[128 * 64];
    GEMM_PRE();
    const int row0 = (int)(f / gx) * 128;
    const int bxs = (int)(f % gx);
    const int wtrow0 = bxs * 128;
    const int page = bxs >> 2;
    const int colp0 = (bxs & 3) * 128;
    u16* C = (page == 0) ? c0 : (page == 1) ? c1 : c2;
    f32x4 acc[4][4] = {};

    for (int kt = 0; kt < 512; kt += 64) {
#pragma unroll
        for (int j = 0; j < 4; ++j) {
            const int line = w * 32 + j * 8;
            const u16* asrc = A  + (size_t)(row0 + line + lrow) * 512 + kt + swz8;
            const u16* bsrc = WT + (size_t)(wtrow0 + line + lrow) * 512 + kt + swz8;
            __builtin_amdgcn_global_load_lds((glb_u32*)asrc, (lds_u32*)&As[line * 64], 16, 0, 0);
            __builtin_amdgcn_global_load_lds((glb_u32*)bsrc, (lds_u32*)&Bs[line * 64], 16, 0, 0);
        }
        __syncthreads();
        GEMM_COMPUTE();
        __syncthreads();
    }
    const int crow = kq * 4;
#pragma unroll
    for (int i = 0; i < 4; ++i)
#pragma unroll
        for (int j = 0; j < 4; ++j) {
            const int col = colp0 + wc * 64 + j * 16 + fr16;
            const float bv = bias[wtrow0 + wc * 64 + j * 16 + fr16];
#pragma unroll
            for (int e = 0; e < 4; ++e) {
                const size_t r = (size_t)(row0 + wr * 64 + i * 16 + crow + e);
                C[r * 512 + col] = (u16)f2bfbits(acc[i][j][e] + bv);
            }
        }
}

// ---------------- MFMA attention (round-4/5, verified) ----------------
__global__ __launch_bounds__(384)
void attn_mfma(const u16* __restrict__ q, const u16* __restrict__ kbuf,
               const u16* __restrict__ vbuf, const float* __restrict__ mask,
               u16* __restrict__ out, int time_axis)
{
    __shared__ __align__(16) u16 Ks[96][72];
    __shared__ __align__(16) u16 VT[64][104];
    __shared__ __align__(16) u16 Ps[96][104];
    const int g = blockIdx.x;
    const int h = g & 7;
    const int bs = g >> 3;
    const int b = bs / 96, st = bs % 96;
    const size_t base   = time_axis ? ((size_t)(b * 96 + st) * 96) : ((size_t)b * 9216 + st);
    const size_t stride = time_axis ? 1 : 96;
    const int tid = threadIdx.x;
    const int w = tid / 64, l = tid & 63;
    const int fr = l & 15, fk = (l >> 4) * 8;

    for (int task = tid; task < 96 * 8; task += 384) {
        const int r = task >> 3, c = task & 7;
        *(uint4*)&Ks[r][c * 8] =
            *(const uint4*)(kbuf + (base + (size_t)r * stride) * 512 + h * 64 + c * 8);
    }
    for (int task = tid; task < 96 * 8; task += 384) {
        const int r = task >> 3, c = task & 7;
        uint4 dv = *(const uint4*)(vbuf + (base + (size_t)r * stride) * 512 + h * 64 + c * 8);
        const u16* e = (const u16*)&dv;
#pragma unroll
        for (int j = 0; j < 8; ++j) VT[c * 8 + j][r] = e[j];
    }
    const u16* qp = q + (base + (size_t)(16 * w + fr) * stride) * 512 + h * 64;
    bf16x8 aq0 = *(const bf16x8*)(qp + fk);
    bf16x8 aq1 = *(const bf16x8*)(qp + 32 + fk);
    __syncthreads();

    f32x4 s[6] = {};
#pragma unroll
    for (int fc = 0; fc < 6; ++fc) {
        bf16x8 b0 = *(const bf16x8*)&Ks[fc * 16 + fr][fk];
        bf16x8 b1 = *(const bf16x8*)&Ks[fc * 16 + fr][32 + fk];
        s[fc] = __builtin_amdgcn_mfma_f32_16x16x32_bf16(aq0, b0, s[fc], 0, 0, 0);
        s[fc] = __builtin_amdgcn_mfma_f32_16x16x32_bf16(aq1, b1, s[fc], 0, 0, 0);
    }
    float mrow[4], lrow[4];
#pragma unroll
    for (int e = 0; e < 4; ++e) {
        float mx = s[0][e];
#pragma unroll
        for (int fc = 1; fc < 6; ++fc) mx = fmaxf(mx, s[fc][e]);
#pragma unroll
        for (int off = 1; off < 16; off <<= 1) mx = fmaxf(mx, __shfl_xor(mx, off));
        mrow[e] = mx * 0.125f;
        lrow[e] = 0.f;
    }
    const int e0 = (l >> 4) * 4;
#pragma unroll
    for (int fc = 0; fc < 6; ++fc) {
#pragma unroll
        for (int e = 0; e < 4; ++e) {
            const float p = __expf(fmaf(s[fc][e], 0.125f, -mrow[e]));
            lrow[e] += p;
            Ps[16 * w + e0 + e][fc * 16 + fr] = (u16)f2bfbits(p);
        }
    }
#pragma unroll
    for (int e = 0; e < 4; ++e)
#pragma unroll
        for (int off = 1; off < 16; off <<= 1) lrow[e] += __shfl_xor(lrow[e], off);

    __syncthreads();

    f32x4 oacc[4] = {};
#pragma unroll
    for (int ks = 0; ks < 3; ++ks) {
        bf16x8 ap = *(const bf16x8*)&Ps[16 * w + fr][ks * 32 + fk];
#pragma unroll
        for (int j = 0; j < 4; ++j) {
            bf16x8 bv = *(const bf16x8*)&VT[j * 16 + fr][ks * 32 + fk];
            oacc[j] = __builtin_amdgcn_mfma_f32_16x16x32_bf16(ap, bv, oacc[j], 0, 0, 0);
        }
    }
    float mk[4];
#pragma unroll
    for (int e = 0; e < 4; ++e) {
        const size_t qrow = base + (size_t)(16 * w + e0 + e) * stride;
        mk[e] = mask[qrow] / lrow[e];
    }
#pragma unroll
    for (int j = 0; j < 4; ++j)
#pragma unroll
        for (int e = 0; e < 4; ++e) {
            const size_t qrow = base + (size_t)(16 * w + e0 + e) * stride;
            out[qrow * 512 + h * 64 + j * 16 + fr] = (u16)f2bfbits(oacc[j][e] * mk[e]);
        }
}

// ---------------- residual add + LayerNorm (one wave per row of 512) ----------------
template<typename TA, typename TB, typename TO>
__global__ __launch_bounds__(64)
void add_ln(const TA* __restrict__ a, const TB* __restrict__ bsrc,
            const float* __restrict__ g, const float* __restrict__ beta,
            TO* __restrict__ out)
{
    const size_t row = blockIdx.x;
    const int lane = threadIdx.x;
    float ya[8], yb[8], y[8];
    load8(a + row * D_ + lane * 8, ya);
    load8(bsrc + row * D_ + lane * 8, yb);
    float sum = 0.f, sq = 0.f;
#pragma unroll
    for (int i = 0; i < 8; ++i) { y[i] = ya[i] + yb[i]; sum += y[i]; sq += y[i] * y[i]; }
#pragma unroll
    for (int off = 32; off >= 1; off >>= 1) {
        sum += __shfl_xor(sum, off);
        sq  += __shfl_xor(sq, off);
    }
    const float mean = sum * (1.f / D_);
    const float var  = sq * (1.f / D_) - mean * mean;
    const float rstd = rsqrtf(var + EPS_);
    const float* gp = g + lane * 8;
    const float* bp = beta + lane * 8;
    float o[8];
#pragma unroll
    for (int i = 0; i < 8; ++i) o[i] = (y[i] - mean) * rstd * gp[i] + bp[i];
    store8(out + row * D_ + lane * 8, o);
}

extern "C" void kernel_launch(void* const* d_in, const int* in_sizes, int n_in,
                              void* d_out, int out_size, void* d_ws, size_t ws_size,
                              hipStream_t stream)
{
    const float* x     = (const float*)d_in[0];
    const float* mask  = (const float*)d_in[1];
    const float* t_w   = (const float*)d_in[2];
    const float* t_b   = (const float*)d_in[3];
    const float* s_w   = (const float*)d_in[4];
    const float* s_b   = (const float*)d_in[5];
    const float* fc_w1 = (const float*)d_in[6];
    const float* fc_b1 = (const float*)d_in[7];
    const float* fc_w2 = (const float*)d_in[8];
    const float* fc_b2 = (const float*)d_in[9];
    const float* ln1_g = (const float*)d_in[10];
    const float* ln1_b = (const float*)d_in[11];
    const float* ln2_g = (const float*)d_in[12];
    const float* ln2_b = (const float*)d_in[13];

    const size_t PG = (size_t)NROWS * 512;
    const size_t WTC = (size_t)2048 * 512 * 2;   // fc weight tail (elements)
    if (ws_size < (PG * 3 + WTC) * sizeof(u16)) return;  // proven available (round 5 ran)
    u16* O0  = (u16*)d_out;                       // pages in d_out (scratch until final LN)
    u16* O1  = O0 + PG;
    u16* WS0 = (u16*)d_ws;
    u16* WS1 = WS0 + PG;
    u16* WS2 = WS1 + PG;
    u16* WT1f = WS0 + 3 * PG;                     // fc_w1^T (2048 x 512)
    u16* WT2f = WT1f + (size_t)2048 * 512;        // fc_w2^T (512 x 2048)

    const dim3 gblk(256);
    const dim3 g512(4, NROWS / 128);
    const dim3 g1024(8, NROWS / 128);
    const dim3 qkvgrid(12, NROWS / 128);
    const dim3 t512(16, 16);

    // x -> bf16 (WS2)
    cvt_f32_bf16<<<dim3((unsigned)(PG / 2048)), gblk, 0, stream>>>(x, WS2);
    // t_w[0..2] -> WT bf16 in O1 (contiguous 1536 x 512)
    for (int i = 0; i < 3; ++i)
        tconv<<<t512, gblk, 0, stream>>>(t_w + (size_t)i * DD_, O1 + (size_t)i * DD_, 512, 512);
    // time QKV: q->O0, k->WS0, v->WS1
    gemm_qkv<<<qkvgrid, gblk, 0, stream>>>(WS2, O1, t_b, O0, WS0, WS1);
    // t_w3, s_w0..3 -> WT bf16 in WS2 (xb dead)
    tconv<<<t512, gblk, 0, stream>>>(t_w + (size_t)3 * DD_, WS2, 512, 512);
    for (int i = 0; i < 4; ++i)
        tconv<<<t512, gblk, 0, stream>>>(s_w + (size_t)i * DD_, WS2 + (size_t)(1 + i) * DD_, 512, 512);
    attn_mfma<<<dim3(B_ * H_ * 96), dim3(384), 0, stream>>>(O0, WS0, WS1, mask, O0, 1);
    gemm2<0, false, u16><<<g512, gblk, 0, stream>>>(O0, WS2, t_b + 3 * 512, O1, 512, 512, 512, 512);  // tt
    // space QKV
    gemm_qkv<<<qkvgrid, gblk, 0, stream>>>(O1, WS2 + (size_t)DD_, s_b, O0, WS0, WS1);
    attn_mfma<<<dim3(B_ * H_ * 96), dim3(384), 0, stream>>>(O0, WS0, WS1, mask, O0, 0);
    gemm2<0, false, u16><<<g512, gblk, 0, stream>>>(O0, WS2 + (size_t)4 * DD_, s_b + 3 * 512, O1, 512, 512, 512, 512); // ss
    // LN1: x1 = LN(x + ss) -> WS0
    add_ln<float, u16, u16><<<dim3(NROWS), dim3(64), 0, stream>>>(x, O1, ln1_g, ln1_b, WS0);
    // fc WTs -> ws tail
    tconv<<<dim3(64, 16), gblk, 0, stream>>>(fc_w1, WT1f, 512, 2048);
    tconv<<<dim3(16, 64), gblk, 0, stream>>>(fc_w2, WT2f, 2048, 512);
    // ---- FFN in 2 FF-chunks; every dispatch has disjoint read/write buffers ----
    // chunk 0: hA = leaky(x1 @ W1[:,0:1024]) -> O0:O1 (rows x 1024 bf16)
    gemm2<1, false, u16><<<g1024, gblk, 0, stream>>>(WS0, WT1f, fc_b1, O0, 512, 512, 512, 1024);
    //          ffA = hA @ W2[0:1024,:] + b2 -> WS1 (reads d_out, writes d_ws)
    gemm2<0, false, u16><<<g512, gblk, 0, stream>>>(O0, WT2f, fc_b2, WS1, 1024, 1024, 2048, 512);
    // chunk 1: hB -> O0:O1 (overwrite; WS1 untouched)
    gemm2<1, false, u16><<<g1024, gblk, 0, stream>>>(WS0, WT1f + (size_t)1024 * 512, fc_b1 + 1024, O0, 512, 512, 512, 1024);
    //          ff += hB @ W2[1024:2048,:] -> WS1 in-place ACC (per-element RMW, proven)
    gemm2<0, true, u16><<<g512, gblk, 0, stream>>>(O0, WT2f + 1024, nullptr, WS1, 1024, 1024, 2048, 512);
    // LN2: out = LN(x1 + ff) -> fp32 d_out (sources WS0/WS1 in d_ws only)
    add_ln<u16, u16, float><<<dim3(NROWS), dim3(64), 0, stream>>>(
        WS0, WS1, ln2_g, ln2_b, (float*)d_out);
}

// Round 8
// 621.751 us; speedup vs baseline: 7.4288x; 1.0224x over previous
//
#include <hip/hip_runtime.h>
#include <hip/hip_bf16.h>

#define B_ 4
#define S_ 96
#define T_ 96
#define D_ 512
#define H_ 8
#define FF_ 2048
#define NROWS (B_*S_*T_)   // 36864
#define EPS_ 1e-5f
#define NEG_ 0.01f
#define DD_ (512*512)

typedef unsigned short u16;   // bf16 bits
typedef __attribute__((ext_vector_type(8))) short bf16x8;
typedef __attribute__((ext_vector_type(4))) float f32x4;
typedef __attribute__((address_space(1))) const unsigned glb_u32;
typedef __attribute__((address_space(3))) unsigned lds_u32;

__device__ __forceinline__ float bf(u16 u) { return __uint_as_float(((unsigned)u) << 16); }
__device__ __forceinline__ u16 f2bf(float f) {            // HW cvt (v_cvt_pk path), RNE
    __hip_bfloat16 h = __float2bfloat16(f);
    return *reinterpret_cast<u16*>(&h);
}
__device__ __forceinline__ float blo(unsigned v) { return __uint_as_float(v << 16); }
__device__ __forceinline__ float bhi(unsigned v) { return __uint_as_float(v & 0xffff0000u); }

__device__ __forceinline__ float cvt_ld(float x) { return x; }
__device__ __forceinline__ float cvt_ld(u16 x)  { return bf(x); }
__device__ __forceinline__ void cvt_st(float* p, float v) { *p = v; }
__device__ __forceinline__ void cvt_st(u16* p, float v)   { *p = f2bf(v); }

__device__ __forceinline__ void load8(const float* p, float* y) {
    float4 a = *(const float4*)p, b = *(const float4*)(p + 4);
    y[0]=a.x; y[1]=a.y; y[2]=a.z; y[3]=a.w; y[4]=b.x; y[5]=b.y; y[6]=b.z; y[7]=b.w;
}
__device__ __forceinline__ void load8(const u16* p, float* y) {
    uint4 u = *(const uint4*)p;
    y[0]=blo(u.x); y[1]=bhi(u.x); y[2]=blo(u.y); y[3]=bhi(u.y);
    y[4]=blo(u.z); y[5]=bhi(u.z); y[6]=blo(u.w); y[7]=bhi(u.w);
}
__device__ __forceinline__ void store8(float* p, const float* y) {
    *(float4*)p       = make_float4(y[0], y[1], y[2], y[3]);
    *(float4*)(p + 4) = make_float4(y[4], y[5], y[6], y[7]);
}
__device__ __forceinline__ void store8(u16* p, const float* y) {
    ushort4 a, b;
    a.x = f2bf(y[0]); a.y = f2bf(y[1]); a.z = f2bf(y[2]); a.w = f2bf(y[3]);
    b.x = f2bf(y[4]); b.y = f2bf(y[5]); b.z = f2bf(y[6]); b.w = f2bf(y[7]);
    *(ushort4*)p = a; *(ushort4*)(p + 4) = b;
}

// ---------------- fp32 -> bf16 elementwise ----------------
__global__ __launch_bounds__(256)
void cvt_f32_bf16(const float* __restrict__ in, u16* __restrict__ out)
{
    const size_t i = ((size_t)blockIdx.x * 256 + threadIdx.x) * 8;
    float y[8];
    load8(in + i, y);
    store8(out + i, y);
}

// ---------------- transpose + convert: out[C x R] bf16 = in[R x C]^T ----------------
__global__ __launch_bounds__(256)
void tconv(const float* __restrict__ in, u16* __restrict__ out, int R, int C)
{
    __shared__ float t[32][33];
    const int c0 = blockIdx.x * 32, r0 = blockIdx.y * 32;
    const int tr = threadIdx.x >> 3, c4 = (threadIdx.x & 7) * 4;
    float4 v = *(const float4*)(in + (size_t)(r0 + tr) * C + c0 + c4);
    t[tr][c4] = v.x; t[tr][c4 + 1] = v.y; t[tr][c4 + 2] = v.z; t[tr][c4 + 3] = v.w;
    __syncthreads();
    const int oc = tr, r4 = c4;
    ushort4 u;
    u.x = f2bf(t[r4 + 0][oc]); u.y = f2bf(t[r4 + 1][oc]);
    u.z = f2bf(t[r4 + 2][oc]); u.w = f2bf(t[r4 + 3][oc]);
    *(ushort4*)(out + (size_t)(c0 + oc) * R + r0 + r4) = u;
}

// ======== 128^2 GEMM machinery (verified rounds 6-7): single-buffer 32 KB,
// XOR bank-deswizzle (both-sides), XCD-chunked grid swizzle ========
#define GEMM_PRE()                                                              \
    const int tid = threadIdx.x;                                                \
    const int w = tid >> 6, l = tid & 63;                                       \
    const int wr = w >> 1, wc = w & 1;                                          \
    const unsigned gx = gridDim.x;                                              \
    const unsigned nwg = gx * gridDim.y;                                        \
    unsigned f = blockIdx.y * gx + blockIdx.x;                                  \
    f = (f & 7) * (nwg >> 3) + (f >> 3);                                        \
    const int lrow = l >> 3;                                                    \
    const int swz8 = (((l & 7) ^ lrow) << 3);                                   \
    const int fr16 = l & 15;                                                    \
    const int kq = l >> 4;

#define GEMM_COMPUTE()                                                          \
    _Pragma("unroll")                                                           \
    for (int kk = 0; kk < 2; ++kk) {                                            \
        const int sw = ((((kk << 2) | kq)) ^ (fr16 & 7)) << 3;                  \
        bf16x8 af[4], bfr[4];                                                   \
        _Pragma("unroll")                                                       \
        for (int i = 0; i < 4; ++i)                                             \
            af[i] = *(bf16x8*)&As[(wr * 64 + i * 16 + fr16) * 64 + sw];         \
        _Pragma("unroll")                                                       \
        for (int j = 0; j < 4; ++j)                                             \
            bfr[j] = *(bf16x8*)&Bs[(wc * 64 + j * 16 + fr16) * 64 + sw];        \
        _Pragma("unroll")                                                       \
        for (int i = 0; i < 4; ++i)                                             \
            _Pragma("unroll")                                                   \
            for (int j = 0; j < 4; ++j)                                         \
                acc[i][j] = __builtin_amdgcn_mfma_f32_16x16x32_bf16(af[i], bfr[j], acc[i][j], 0, 0, 0); \
    }

// ---------------- gemm2 (128^2): C = act(A @ WT^T + bias | +C) ----------------
template<int ACT, bool ACC, typename TC>
__global__ __launch_bounds__(256)
void gemm2(const u16* __restrict__ A, const u16* __restrict__ WT,
           const float* __restrict__ bias, TC* __restrict__ C,
           int K, int lda, int ldwt, int ldc)
{
    __shared__ u16 As[128 * 64];
    __shared__ u16 Bs[128 * 64];
    GEMM_PRE();
    const int row0 = (int)(f / gx) * 128, col0 = (int)(f % gx) * 128;
    f32x4 acc[4][4] = {};

    for (int kt = 0; kt < K; kt += 64) {
#pragma unroll
        for (int j = 0; j < 4; ++j) {
            const int line = w * 32 + j * 8;
            const u16* asrc = A  + (size_t)(row0 + line + lrow) * lda  + kt + swz8;
            const u16* bsrc = WT + (size_t)(col0 + line + lrow) * ldwt + kt + swz8;
            __builtin_amdgcn_global_load_lds((glb_u32*)asrc, (lds_u32*)&As[line * 64], 16, 0, 0);
            __builtin_amdgcn_global_load_lds((glb_u32*)bsrc, (lds_u32*)&Bs[line * 64], 16, 0, 0);
        }
        __syncthreads();
        GEMM_COMPUTE();
        __syncthreads();
    }
    const int crow = kq * 4;
#pragma unroll
    for (int i = 0; i < 4; ++i)
#pragma unroll
        for (int j = 0; j < 4; ++j) {
            const int col = col0 + wc * 64 + j * 16 + fr16;
            const float bv = ACC ? 0.f : bias[col];
#pragma unroll
            for (int e = 0; e < 4; ++e) {
                const size_t r = (size_t)(row0 + wr * 64 + i * 16 + crow + e);
                TC* cp = &C[r * (size_t)ldc + col];
                float v = acc[i][j][e] + bv;
                if (ACC) v += cvt_ld(*cp);
                if (ACT == 1) v = (v >= 0.f) ? v : NEG_ * v;
                cvt_st(cp, v);
            }
        }
}

// ================= gemm3: 256x256 tile, BK=64, 2-phase counted-vmcnt =================
// 512 threads = 8 waves (2 row-groups x 4 col-groups); per-wave output 128x64.
// LDS 128 KB static: As[2]|Bs[2], each 256x64 u16, same XOR swizzle (both-sides).
// Pipeline: stage(t+1) issued, then s_waitcnt vmcnt(8) (t's 8 loads done, t+1's in
// flight) + raw s_barrier -> compute(t) -> lgkmcnt(0)+sched_barrier+s_barrier.
// Output paging: page = colg>>pgshift (qkv: 9 -> three 512-wide pages; else 30).
template<int ACT, typename TC>
__global__ __launch_bounds__(512)
void gemm3(const u16* __restrict__ A, const u16* __restrict__ WT,
           const float* __restrict__ bias,
           TC* __restrict__ p0, TC* __restrict__ p1, TC* __restrict__ p2,
           int K, int lda, int ldwt, int ldc, int pgshift)
{
    __shared__ u16 lds[65536];   // 128 KB
    const int tid = threadIdx.x;
    const int w = tid >> 6, l = tid & 63;
    const int wr = w >> 2, wc = w & 3;
    const unsigned gx = gridDim.x;
    const unsigned nwg = gx * gridDim.y;
    unsigned f = blockIdx.y * gx + blockIdx.x;
    f = (f & 7) * (nwg >> 3) + (f >> 3);
    const int row0 = (int)(f / gx) * 256, colg0 = (int)(f % gx) * 256;
    const int lrow = l >> 3;
    const int swz8 = (((l & 7) ^ lrow) << 3);
    const int fr16 = l & 15;
    const int kq = l >> 4;

    f32x4 acc[8][4] = {};
    const int NT = K >> 6;

    auto stage = [&](int buf, int kt) {
        u16* Ad = lds + buf * 16384;
        u16* Bd = lds + 32768 + buf * 16384;
#pragma unroll
        for (int j = 0; j < 4; ++j) {
            const int lineb = j * 64 + w * 8;          // wave-uniform dest line
            const int srow = lineb + lrow;
            const u16* asrc = A  + (size_t)(row0  + srow) * lda  + kt + swz8;
            const u16* bsrc = WT + (size_t)(colg0 + srow) * ldwt + kt + swz8;
            __builtin_amdgcn_global_load_lds((glb_u32*)asrc, (lds_u32*)&Ad[lineb * 64], 16, 0, 0);
            __builtin_amdgcn_global_load_lds((glb_u32*)bsrc, (lds_u32*)&Bd[lineb * 64], 16, 0, 0);
        }
    };

    stage(0, 0);
    for (int t = 0; t < NT; ++t) {
        const int cur = t & 1;
        if (t + 1 < NT) {
            stage(cur ^ 1, (t + 1) << 6);
            asm volatile("s_waitcnt vmcnt(8)" ::: "memory");   // wait only buf[cur]'s 8
        } else {
            asm volatile("s_waitcnt vmcnt(0)" ::: "memory");
        }
        __builtin_amdgcn_s_barrier();
        asm volatile("" ::: "memory");
        const u16* Ab = lds + cur * 16384;
        const u16* Bb = lds + 32768 + cur * 16384;
        __builtin_amdgcn_s_setprio(1);
#pragma unroll
        for (int kk = 0; kk < 2; ++kk) {
            const int sw = ((((kk << 2) | kq)) ^ (fr16 & 7)) << 3;
            bf16x8 bfr[4];
#pragma unroll
            for (int j = 0; j < 4; ++j)
                bfr[j] = *(bf16x8*)&Bb[(wc * 64 + j * 16 + fr16) * 64 + sw];
#pragma unroll
            for (int i = 0; i < 8; ++i) {
                bf16x8 af = *(bf16x8*)&Ab[(wr * 128 + i * 16 + fr16) * 64 + sw];
#pragma unroll
                for (int j = 0; j < 4; ++j)
                    acc[i][j] = __builtin_amdgcn_mfma_f32_16x16x32_bf16(af, bfr[j], acc[i][j], 0, 0, 0);
            }
        }
        __builtin_amdgcn_s_setprio(0);
        asm volatile("s_waitcnt lgkmcnt(0)" ::: "memory");
        __builtin_amdgcn_sched_barrier(0);
        __builtin_amdgcn_s_barrier();                          // protect buf[cur] from restage
    }
    // epilogue
    const int crow = kq * 4;
#pragma unroll
    for (int i = 0; i < 8; ++i)
#pragma unroll
        for (int j = 0; j < 4; ++j) {
            const int colg = colg0 + wc * 64 + j * 16 + fr16;
            TC* Cb = (((unsigned)colg >> pgshift) == 0) ? p0
                   : (((unsigned)colg >> pgshift) == 1) ? p1 : p2;
            const int col = colg & ((1 << pgshift) - 1);
            const float bv = bias[colg];
#pragma unroll
            for (int e = 0; e < 4; ++e) {
                const size_t r = (size_t)(row0 + wr * 128 + i * 16 + crow + e);
                float v = acc[i][j][e] + bv;
                if (ACT == 1) v = (v >= 0.f) ? v : NEG_ * v;
                cvt_st(&Cb[r * (size_t)ldc + col], v);
            }
        }
}

// ---------------- MFMA attention (rounds 4-7, verified) ----------------
__global__ __launch_bounds__(384)
void attn_mfma(const u16* __restrict__ q, const u16* __restrict__ kbuf,
               const u16* __restrict__ vbuf, const float* __restrict__ mask,
               u16* __restrict__ out, int time_axis)
{
    __shared__ __align__(16) u16 Ks[96][72];
    __shared__ __align__(16) u16 VT[64][104];
    __shared__ __align__(16) u16 Ps[96][104];
    const int g = blockIdx.x;
    const int h = g & 7;
    const int bs = g >> 3;
    const int b = bs / 96, st = bs % 96;
    const size_t base   = time_axis ? ((size_t)(b * 96 + st) * 96) : ((size_t)b * 9216 + st);
    const size_t stride = time_axis ? 1 : 96;
    const int tid = threadIdx.x;
    const int w = tid / 64, l = tid & 63;
    const int fr = l & 15, fk = (l >> 4) * 8;

    for (int task = tid; task < 96 * 8; task += 384) {
        const int r = task >> 3, c = task & 7;
        *(uint4*)&Ks[r][c * 8] =
            *(const uint4*)(kbuf + (base + (size_t)r * stride) * 512 + h * 64 + c * 8);
    }
    for (int task = tid; task < 96 * 8; task += 384) {
        const int r = task >> 3, c = task & 7;
        uint4 dv = *(const uint4*)(vbuf + (base + (size_t)r * stride) * 512 + h * 64 + c * 8);
        const u16* e = (const u16*)&dv;
#pragma unroll
        for (int j = 0; j < 8; ++j) VT[c * 8 + j][r] = e[j];
    }
    const u16* qp = q + (base + (size_t)(16 * w + fr) * stride) * 512 + h * 64;
    bf16x8 aq0 = *(const bf16x8*)(qp + fk);
    bf16x8 aq1 = *(const bf16x8*)(qp + 32 + fk);
    __syncthreads();

    f32x4 s[6] = {};
#pragma unroll
    for (int fc = 0; fc < 6; ++fc) {
        bf16x8 b0 = *(const bf16x8*)&Ks[fc * 16 + fr][fk];
        bf16x8 b1 = *(const bf16x8*)&Ks[fc * 16 + fr][32 + fk];
        s[fc] = __builtin_amdgcn_mfma_f32_16x16x32_bf16(aq0, b0, s[fc], 0, 0, 0);
        s[fc] = __builtin_amdgcn_mfma_f32_16x16x32_bf16(aq1, b1, s[fc], 0, 0, 0);
    }
    float mrow[4], lrow[4];
#pragma unroll
    for (int e = 0; e < 4; ++e) {
        float mx = s[0][e];
#pragma unroll
        for (int fc = 1; fc < 6; ++fc) mx = fmaxf(mx, s[fc][e]);
#pragma unroll
        for (int off = 1; off < 16; off <<= 1) mx = fmaxf(mx, __shfl_xor(mx, off));
        mrow[e] = mx * 0.125f;
        lrow[e] = 0.f;
    }
    const int e0 = (l >> 4) * 4;
#pragma unroll
    for (int fc = 0; fc < 6; ++fc) {
#pragma unroll
        for (int e = 0; e < 4; ++e) {
            const float p = __expf(fmaf(s[fc][e], 0.125f, -mrow[e]));
            lrow[e] += p;
            Ps[16 * w + e0 + e][fc * 16 + fr] = f2bf(p);
        }
    }
#pragma unroll
    for (int e = 0; e < 4; ++e)
#pragma unroll
        for (int off = 1; off < 16; off <<= 1) lrow[e] += __shfl_xor(lrow[e], off);

    __syncthreads();

    f32x4 oacc[4] = {};
#pragma unroll
    for (int ks = 0; ks < 3; ++ks) {
        bf16x8 ap = *(const bf16x8*)&Ps[16 * w + fr][ks * 32 + fk];
#pragma unroll
        for (int j = 0; j < 4; ++j) {
            bf16x8 bv = *(const bf16x8*)&VT[j * 16 + fr][ks * 32 + fk];
            oacc[j] = __builtin_amdgcn_mfma_f32_16x16x32_bf16(ap, bv, oacc[j], 0, 0, 0);
        }
    }
    float mk[4];
#pragma unroll
    for (int e = 0; e < 4; ++e) {
        const size_t qrow = base + (size_t)(16 * w + e0 + e) * stride;
        mk[e] = mask[qrow] / lrow[e];
    }
#pragma unroll
    for (int j = 0; j < 4; ++j)
#pragma unroll
        for (int e = 0; e < 4; ++e) {
            const size_t qrow = base + (size_t)(16 * w + e0 + e) * stride;
            out[qrow * 512 + h * 64 + j * 16 + fr] = f2bf(oacc[j][e] * mk[e]);
        }
}

// ---------------- residual add + LayerNorm (one wave per row of 512) ----------------
template<typename TA, typename TB, typename TO>
__global__ __launch_bounds__(64)
void add_ln(const TA* __restrict__ a, const TB* __restrict__ bsrc,
            const float* __restrict__ g, const float* __restrict__ beta,
            TO* __restrict__ out)
{
    const size_t row = blockIdx.x;
    const int lane = threadIdx.x;
    float ya[8], yb[8], y[8];
    load8(a + row * D_ + lane * 8, ya);
    load8(bsrc + row * D_ + lane * 8, yb);
    float sum = 0.f, sq = 0.f;
#pragma unroll
    for (int i = 0; i < 8; ++i) { y[i] = ya[i] + yb[i]; sum += y[i]; sq += y[i] * y[i]; }
#pragma unroll
    for (int off = 32; off >= 1; off >>= 1) {
        sum += __shfl_xor(sum, off);
        sq  += __shfl_xor(sq, off);
    }
    const float mean = sum * (1.f / D_);
    const float var  = sq * (1.f / D_) - mean * mean;
    const float rstd = rsqrtf(var + EPS_);
    const float* gp = g + lane * 8;
    const float* bp = beta + lane * 8;
    float o[8];
#pragma unroll
    for (int i = 0; i < 8; ++i) o[i] = (y[i] - mean) * rstd * gp[i] + bp[i];
    store8(out + row * D_ + lane * 8, o);
}

extern "C" void kernel_launch(void* const* d_in, const int* in_sizes, int n_in,
                              void* d_out, int out_size, void* d_ws, size_t ws_size,
                              hipStream_t stream)
{
    const float* x     = (const float*)d_in[0];
    const float* mask  = (const float*)d_in[1];
    const float* t_w   = (const float*)d_in[2];
    const float* t_b   = (const float*)d_in[3];
    const float* s_w   = (const float*)d_in[4];
    const float* s_b   = (const float*)d_in[5];
    const float* fc_w1 = (const float*)d_in[6];
    const float* fc_b1 = (const float*)d_in[7];
    const float* fc_w2 = (const float*)d_in[8];
    const float* fc_b2 = (const float*)d_in[9];
    const float* ln1_g = (const float*)d_in[10];
    const float* ln1_b = (const float*)d_in[11];
    const float* ln2_g = (const float*)d_in[12];
    const float* ln2_b = (const float*)d_in[13];

    const size_t PG = (size_t)NROWS * 512;
    const size_t WTC = (size_t)2048 * 512 * 2;
    if (ws_size < (PG * 3 + WTC) * sizeof(u16)) return;
    u16* O0  = (u16*)d_out;
    u16* O1  = O0 + PG;
    u16* WS0 = (u16*)d_ws;
    u16* WS1 = WS0 + PG;
    u16* WS2 = WS1 + PG;
    u16* WT1f = WS0 + 3 * PG;                     // fc_w1^T (2048 x 512)
    u16* WT2f = WT1f + (size_t)2048 * 512;        // fc_w2^T (512 x 2048)

    const dim3 gblk(256);
    const dim3 g512(4, NROWS / 128);
    const dim3 qkv3grid(6, NROWS / 256);          // gemm3: N=1536
    const dim3 h3grid(4, NROWS / 256);            // gemm3: N=1024
    const dim3 t512(16, 16);

    // x -> bf16 (WS2)
    cvt_f32_bf16<<<dim3((unsigned)(PG / 2048)), gblk, 0, stream>>>(x, WS2);
    // t_w[0..2] -> WT bf16 in O1 (contiguous 1536 x 512)
    for (int i = 0; i < 3; ++i)
        tconv<<<t512, gblk, 0, stream>>>(t_w + (size_t)i * DD_, O1 + (size_t)i * DD_, 512, 512);
    // time QKV: q->O0, k->WS0, v->WS1
    gemm3<0, u16><<<qkv3grid, dim3(512), 0, stream>>>(
        WS2, O1, t_b, O0, WS0, WS1, 512, 512, 512, 512, 9);
    // t_w3, s_w0..3 -> WT bf16 in WS2 (xb dead)
    tconv<<<t512, gblk, 0, stream>>>(t_w + (size_t)3 * DD_, WS2, 512, 512);
    for (int i = 0; i < 4; ++i)
        tconv<<<t512, gblk, 0, stream>>>(s_w + (size_t)i * DD_, WS2 + (size_t)(1 + i) * DD_, 512, 512);
    attn_mfma<<<dim3(B_ * H_ * 96), dim3(384), 0, stream>>>(O0, WS0, WS1, mask, O0, 1);
    gemm2<0, false, u16><<<g512, gblk, 0, stream>>>(O0, WS2, t_b + 3 * 512, O1, 512, 512, 512, 512);  // tt
    // space QKV
    gemm3<0, u16><<<qkv3grid, dim3(512), 0, stream>>>(
        O1, WS2 + (size_t)DD_, s_b, O0, WS0, WS1, 512, 512, 512, 512, 9);
    attn_mfma<<<dim3(B_ * H_ * 96), dim3(384), 0, stream>>>(O0, WS0, WS1, mask, O0, 0);
    gemm2<0, false, u16><<<g512, gblk, 0, stream>>>(O0, WS2 + (size_t)4 * DD_, s_b + 3 * 512, O1, 512, 512, 512, 512); // ss
    // LN1: x1 = LN(x + ss) -> WS0
    add_ln<float, u16, u16><<<dim3(NROWS), dim3(64), 0, stream>>>(x, O1, ln1_g, ln1_b, WS0);
    // fc WTs -> ws tail
    tconv<<<dim3(64, 16), gblk, 0, stream>>>(fc_w1, WT1f, 512, 2048);
    tconv<<<dim3(16, 64), gblk, 0, stream>>>(fc_w2, WT2f, 2048, 512);
    // ---- FFN in 2 FF-chunks; disjoint read/write buffers per dispatch ----
    // chunk 0: hA = leaky(x1 @ W1[:,0:1024]) -> O0:O1 (rows x 1024 bf16)
    gemm3<1, u16><<<h3grid, dim3(512), 0, stream>>>(
        WS0, WT1f, fc_b1, O0, O0, O0, 512, 512, 512, 1024, 30);
    //          ffA = hA @ W2[0:1024,:] + b2 -> WS1
    gemm2<0, false, u16><<<g512, gblk, 0, stream>>>(O0, WT2f, fc_b2, WS1, 1024, 1024, 2048, 512);
    // chunk 1: hB -> O0:O1 (overwrite; WS1 untouched)
    gemm3<1, u16><<<h3grid, dim3(512), 0, stream>>>(
        WS0, WT1f + (size_t)1024 * 512, fc_b1 + 1024, O0, O0, O0, 512, 512, 512, 1024, 30);
    //          ff += hB @ W2[1024:2048,:] -> WS1 in-place ACC
    gemm2<0, true, u16><<<g512, gblk, 0, stream>>>(O0, WT2f + 1024, nullptr, WS1, 1024, 1024, 2048, 512);
    // LN2: out = LN(x1 + ff) -> fp32 d_out (sources in d_ws only)
    add_ln<u16, u16, float><<<dim3(NROWS), dim3(64), 0, stream>>>(
        WS0, WS1, ln2_g, ln2_b, (float*)d_out);
}

// Round 9
// 568.496 us; speedup vs baseline: 8.1247x; 1.0937x over previous
//
#include <hip/hip_runtime.h>
#include <hip/hip_bf16.h>

#define B_ 4
#define S_ 96
#define T_ 96
#define D_ 512
#define H_ 8
#define FF_ 2048
#define NROWS (B_*S_*T_)   // 36864
#define EPS_ 1e-5f
#define NEG_ 0.01f
#define DD_ (512*512)

typedef unsigned short u16;   // bf16 bits
typedef __attribute__((ext_vector_type(8))) short bf16x8;
typedef __attribute__((ext_vector_type(4))) float f32x4;
typedef __attribute__((address_space(1))) const unsigned glb_u32;
typedef __attribute__((address_space(3))) unsigned lds_u32;

__device__ __forceinline__ float bf(u16 u) { return __uint_as_float(((unsigned)u) << 16); }
__device__ __forceinline__ u16 f2bf(float f) {
    __hip_bfloat16 h = __float2bfloat16(f);
    return *reinterpret_cast<u16*>(&h);
}
__device__ __forceinline__ float blo(unsigned v) { return __uint_as_float(v << 16); }
__device__ __forceinline__ float bhi(unsigned v) { return __uint_as_float(v & 0xffff0000u); }

__device__ __forceinline__ float cvt_ld(float x) { return x; }
__device__ __forceinline__ float cvt_ld(u16 x)  { return bf(x); }
__device__ __forceinline__ void cvt_st(float* p, float v) { *p = v; }
__device__ __forceinline__ void cvt_st(u16* p, float v)   { *p = f2bf(v); }

__device__ __forceinline__ void load8(const float* p, float* y) {
    float4 a = *(const float4*)p, b = *(const float4*)(p + 4);
    y[0]=a.x; y[1]=a.y; y[2]=a.z; y[3]=a.w; y[4]=b.x; y[5]=b.y; y[6]=b.z; y[7]=b.w;
}
__device__ __forceinline__ void load8(const u16* p, float* y) {
    uint4 u = *(const uint4*)p;
    y[0]=blo(u.x); y[1]=bhi(u.x); y[2]=blo(u.y); y[3]=bhi(u.y);
    y[4]=blo(u.z); y[5]=bhi(u.z); y[6]=blo(u.w); y[7]=bhi(u.w);
}
__device__ __forceinline__ void store8(float* p, const float* y) {
    *(float4*)p       = make_float4(y[0], y[1], y[2], y[3]);
    *(float4*)(p + 4) = make_float4(y[4], y[5], y[6], y[7]);
}
__device__ __forceinline__ void store8(u16* p, const float* y) {
    ushort4 a, b;
    a.x = f2bf(y[0]); a.y = f2bf(y[1]); a.z = f2bf(y[2]); a.w = f2bf(y[3]);
    b.x = f2bf(y[4]); b.y = f2bf(y[5]); b.z = f2bf(y[6]); b.w = f2bf(y[7]);
    *(ushort4*)p = a; *(ushort4*)(p + 4) = b;
}

// ---------------- fp32 -> bf16 elementwise ----------------
__global__ __launch_bounds__(256)
void cvt_f32_bf16(const float* __restrict__ in, u16* __restrict__ out)
{
    const size_t i = ((size_t)blockIdx.x * 256 + threadIdx.x) * 8;
    float y[8];
    load8(in + i, y);
    store8(out + i, y);
}

// ---------------- transpose + convert (generic) ----------------
__global__ __launch_bounds__(256)
void tconv(const float* __restrict__ in, u16* __restrict__ out, int R, int C)
{
    __shared__ float t[32][33];
    const int c0 = blockIdx.x * 32, r0 = blockIdx.y * 32;
    const int tr = threadIdx.x >> 3, c4 = (threadIdx.x & 7) * 4;
    float4 v = *(const float4*)(in + (size_t)(r0 + tr) * C + c0 + c4);
    t[tr][c4] = v.x; t[tr][c4 + 1] = v.y; t[tr][c4 + 2] = v.z; t[tr][c4 + 3] = v.w;
    __syncthreads();
    const int oc = tr, r4 = c4;
    ushort4 u;
    u.x = f2bf(t[r4 + 0][oc]); u.y = f2bf(t[r4 + 1][oc]);
    u.z = f2bf(t[r4 + 2][oc]); u.w = f2bf(t[r4 + 3][oc]);
    *(ushort4*)(out + (size_t)(c0 + oc) * R + r0 + r4) = u;
}

// ---------------- batched 512x512 transpose: 8 square attn weights -> tail ----------------
// order: [t_w0..3, s_w0..3]
__global__ __launch_bounds__(256)
void tconv8(const float* __restrict__ t_w, const float* __restrict__ s_w,
            u16* __restrict__ out)
{
    __shared__ float t[32][33];
    const int z = blockIdx.z;
    const float* in = (z < 4) ? (t_w + (size_t)z * DD_) : (s_w + (size_t)(z - 4) * DD_);
    u16* o = out + (size_t)z * DD_;
    const int c0 = blockIdx.x * 32, r0 = blockIdx.y * 32;
    const int tr = threadIdx.x >> 3, c4 = (threadIdx.x & 7) * 4;
    float4 v = *(const float4*)(in + (size_t)(r0 + tr) * 512 + c0 + c4);
    t[tr][c4] = v.x; t[tr][c4 + 1] = v.y; t[tr][c4 + 2] = v.z; t[tr][c4 + 3] = v.w;
    __syncthreads();
    const int oc = tr, r4 = c4;
    ushort4 u;
    u.x = f2bf(t[r4 + 0][oc]); u.y = f2bf(t[r4 + 1][oc]);
    u.z = f2bf(t[r4 + 2][oc]); u.w = f2bf(t[r4 + 3][oc]);
    *(ushort4*)(o + (size_t)(c0 + oc) * 512 + r0 + r4) = u;
}

// ======== 128^2 GEMM (verified rounds 6-8, UNCHANGED core): single-buffer 32 KB,
// XOR bank-deswizzle, XCD-chunked swizzle. (Phase-split intentionally NOT applied:
// 8-phase on 128^2/4-wave regressed per m232.) ========
#define GEMM_PRE()                                                              \
    const int tid = threadIdx.x;                                                \
    const int w = tid >> 6, l = tid & 63;                                       \
    const int wr = w >> 1, wc = w & 1;                                          \
    const unsigned gx = gridDim.x;                                              \
    const unsigned nwg = gx * gridDim.y;                                        \
    unsigned f = blockIdx.y * gx + blockIdx.x;                                  \
    f = (f & 7) * (nwg >> 3) + (f >> 3);                                        \
    const int lrow = l >> 3;                                                    \
    const int swz8 = (((l & 7) ^ lrow) << 3);                                   \
    const int fr16 = l & 15;                                                    \
    const int kq = l >> 4;

#define GEMM_COMPUTE()                                                          \
    _Pragma("unroll")                                                           \
    for (int kk = 0; kk < 2; ++kk) {                                            \
        const int sw = ((((kk << 2) | kq)) ^ (fr16 & 7)) << 3;                  \
        bf16x8 af[4], bfr[4];                                                   \
        _Pragma("unroll")                                                       \
        for (int i = 0; i < 4; ++i)                                             \
            af[i] = *(bf16x8*)&As[(wr * 64 + i * 16 + fr16) * 64 + sw];         \
        _Pragma("unroll")                                                       \
        for (int j = 0; j < 4; ++j)                                             \
            bfr[j] = *(bf16x8*)&Bs[(wc * 64 + j * 16 + fr16) * 64 + sw];        \
        _Pragma("unroll")                                                       \
        for (int i = 0; i < 4; ++i)                                             \
            _Pragma("unroll")                                                   \
            for (int j = 0; j < 4; ++j)                                         \
                acc[i][j] = __builtin_amdgcn_mfma_f32_16x16x32_bf16(af[i], bfr[j], acc[i][j], 0, 0, 0); \
    }

template<int ACT, bool ACC, typename TC>
__global__ __launch_bounds__(256)
void gemm2(const u16* __restrict__ A, const u16* __restrict__ WT,
           const float* __restrict__ bias, TC* __restrict__ C,
           int K, int lda, int ldwt, int ldc)
{
    __shared__ u16 As[128 * 64];
    __shared__ u16 Bs[128 * 64];
    GEMM_PRE();
    const int row0 = (int)(f / gx) * 128, col0 = (int)(f % gx) * 128;
    f32x4 acc[4][4] = {};

    for (int kt = 0; kt < K; kt += 64) {
#pragma unroll
        for (int j = 0; j < 4; ++j) {
            const int line = w * 32 + j * 8;
            const u16* asrc = A  + (size_t)(row0 + line + lrow) * lda  + kt + swz8;
            const u16* bsrc = WT + (size_t)(col0 + line + lrow) * ldwt + kt + swz8;
            __builtin_amdgcn_global_load_lds((glb_u32*)asrc, (lds_u32*)&As[line * 64], 16, 0, 0);
            __builtin_amdgcn_global_load_lds((glb_u32*)bsrc, (lds_u32*)&Bs[line * 64], 16, 0, 0);
        }
        __syncthreads();
        GEMM_COMPUTE();
        __syncthreads();
    }
    const int crow = kq * 4;
#pragma unroll
    for (int i = 0; i < 4; ++i)
#pragma unroll
        for (int j = 0; j < 4; ++j) {
            const int col = col0 + wc * 64 + j * 16 + fr16;
            const float bv = ACC ? 0.f : bias[col];
#pragma unroll
            for (int e = 0; e < 4; ++e) {
                const size_t r = (size_t)(row0 + wr * 64 + i * 16 + crow + e);
                TC* cp = &C[r * (size_t)ldc + col];
                float v = acc[i][j][e] + bv;
                if (ACC) v += cvt_ld(*cp);
                if (ACT == 1) v = (v >= 0.f) ? v : NEG_ * v;
                cvt_st(cp, v);
            }
        }
}

// ================= gemm3 v2: 256x256, BK=64, dbuf + counted vmcnt + m201 4-phase =================
// 512 thr = 8 waves (2x4). Per K-tile: gate [vmcnt(8); s_barrier], then 4 phases
// (kk = p>>1, ihalf = p&1): {ds_read 8|4 b128; s_barrier; setprio(1); 16 MFMA; setprio(0)}.
// Stages only touch buf[cur^1]; buf[cur] reads complete via compiler lgkmcnt before MFMA.
template<int ACT, typename TC>
__global__ __launch_bounds__(512)
void gemm3(const u16* __restrict__ A, const u16* __restrict__ WT,
           const float* __restrict__ bias,
           TC* __restrict__ p0, TC* __restrict__ p1, TC* __restrict__ p2,
           int K, int lda, int ldwt, int ldc, int pgshift)
{
    __shared__ u16 lds[65536];   // 128 KB
    const int tid = threadIdx.x;
    const int w = tid >> 6, l = tid & 63;
    const int wr = w >> 2, wc = w & 3;
    const unsigned gx = gridDim.x;
    const unsigned nwg = gx * gridDim.y;
    unsigned f = blockIdx.y * gx + blockIdx.x;
    f = (f & 7) * (nwg >> 3) + (f >> 3);
    const int row0 = (int)(f / gx) * 256, colg0 = (int)(f % gx) * 256;
    const int lrow = l >> 3;
    const int swz8 = (((l & 7) ^ lrow) << 3);
    const int fr16 = l & 15;
    const int kq = l >> 4;

    f32x4 acc[8][4] = {};
    const int NT = K >> 6;

    auto stage = [&](int buf, int kt) {
        u16* Ad = lds + buf * 16384;
        u16* Bd = lds + 32768 + buf * 16384;
#pragma unroll
        for (int j = 0; j < 4; ++j) {
            const int lineb = j * 64 + w * 8;
            const int srow = lineb + lrow;
            const u16* asrc = A  + (size_t)(row0  + srow) * lda  + kt + swz8;
            const u16* bsrc = WT + (size_t)(colg0 + srow) * ldwt + kt + swz8;
            __builtin_amdgcn_global_load_lds((glb_u32*)asrc, (lds_u32*)&Ad[lineb * 64], 16, 0, 0);
            __builtin_amdgcn_global_load_lds((glb_u32*)bsrc, (lds_u32*)&Bd[lineb * 64], 16, 0, 0);
        }
    };

    stage(0, 0);
    for (int t = 0; t < NT; ++t) {
        const int cur = t & 1;
        if (t + 1 < NT) {
            stage(cur ^ 1, (t + 1) << 6);
            asm volatile("s_waitcnt vmcnt(8)" ::: "memory");
        } else {
            asm volatile("s_waitcnt vmcnt(0)" ::: "memory");
        }
        __builtin_amdgcn_s_barrier();                     // gate: buf[cur] published
        const u16* Ab = lds + cur * 16384;
        const u16* Bb = lds + 32768 + cur * 16384;
        bf16x8 bq[4];
#pragma unroll
        for (int p = 0; p < 4; ++p) {
            const int kk = p >> 1, ih = p & 1;
            const int sw = ((((kk << 2) | kq)) ^ (fr16 & 7)) << 3;
            if (ih == 0) {
#pragma unroll
                for (int j = 0; j < 4; ++j)
                    bq[j] = *(bf16x8*)&Bb[(wc * 64 + j * 16 + fr16) * 64 + sw];
            }
            bf16x8 af[4];
#pragma unroll
            for (int i = 0; i < 4; ++i)
                af[i] = *(bf16x8*)&Ab[(wr * 128 + (ih * 4 + i) * 16 + fr16) * 64 + sw];
            __builtin_amdgcn_s_barrier();                 // phase alignment
            __builtin_amdgcn_s_setprio(1);
#pragma unroll
            for (int i = 0; i < 4; ++i)
#pragma unroll
                for (int j = 0; j < 4; ++j)
                    acc[ih * 4 + i][j] = __builtin_amdgcn_mfma_f32_16x16x32_bf16(
                        af[i], bq[j], acc[ih * 4 + i][j], 0, 0, 0);
            __builtin_amdgcn_s_setprio(0);
        }
    }
    // epilogue
    const int crow = kq * 4;
#pragma unroll
    for (int i = 0; i < 8; ++i)
#pragma unroll
        for (int j = 0; j < 4; ++j) {
            const int colg = colg0 + wc * 64 + j * 16 + fr16;
            TC* Cb = (((unsigned)colg >> pgshift) == 0) ? p0
                   : (((unsigned)colg >> pgshift) == 1) ? p1 : p2;
            const int col = colg & ((1 << pgshift) - 1);
            const float bv = bias[colg];
#pragma unroll
            for (int e = 0; e < 4; ++e) {
                const size_t r = (size_t)(row0 + wr * 128 + i * 16 + crow + e);
                float v = acc[i][j][e] + bv;
                if (ACT == 1) v = (v >= 0.f) ? v : NEG_ * v;
                cvt_st(&Cb[r * (size_t)ldc + col], v);
            }
        }
}

// ---------------- MFMA attention (rounds 4-8, verified, unchanged) ----------------
__global__ __launch_bounds__(384)
void attn_mfma(const u16* __restrict__ q, const u16* __restrict__ kbuf,
               const u16* __restrict__ vbuf, const float* __restrict__ mask,
               u16* __restrict__ out, int time_axis)
{
    __shared__ __align__(16) u16 Ks[96][72];
    __shared__ __align__(16) u16 VT[64][104];
    __shared__ __align__(16) u16 Ps[96][104];
    const int g = blockIdx.x;
    const int h = g & 7;
    const int bs = g >> 3;
    const int b = bs / 96, st = bs % 96;
    const size_t base   = time_axis ? ((size_t)(b * 96 + st) * 96) : ((size_t)b * 9216 + st);
    const size_t stride = time_axis ? 1 : 96;
    const int tid = threadIdx.x;
    const int w = tid / 64, l = tid & 63;
    const int fr = l & 15, fk = (l >> 4) * 8;

    for (int task = tid; task < 96 * 8; task += 384) {
        const int r = task >> 3, c = task & 7;
        *(uint4*)&Ks[r][c * 8] =
            *(const uint4*)(kbuf + (base + (size_t)r * stride) * 512 + h * 64 + c * 8);
    }
    for (int task = tid; task < 96 * 8; task += 384) {
        const int r = task >> 3, c = task & 7;
        uint4 dv = *(const uint4*)(vbuf + (base + (size_t)r * stride) * 512 + h * 64 + c * 8);
        const u16* e = (const u16*)&dv;
#pragma unroll
        for (int j = 0; j < 8; ++j) VT[c * 8 + j][r] = e[j];
    }
    const u16* qp = q + (base + (size_t)(16 * w + fr) * stride) * 512 + h * 64;
    bf16x8 aq0 = *(const bf16x8*)(qp + fk);
    bf16x8 aq1 = *(const bf16x8*)(qp + 32 + fk);
    __syncthreads();

    f32x4 s[6] = {};
#pragma unroll
    for (int fc = 0; fc < 6; ++fc) {
        bf16x8 b0 = *(const bf16x8*)&Ks[fc * 16 + fr][fk];
        bf16x8 b1 = *(const bf16x8*)&Ks[fc * 16 + fr][32 + fk];
        s[fc] = __builtin_amdgcn_mfma_f32_16x16x32_bf16(aq0, b0, s[fc], 0, 0, 0);
        s[fc] = __builtin_amdgcn_mfma_f32_16x16x32_bf16(aq1, b1, s[fc], 0, 0, 0);
    }
    float mrow[4], lrow[4];
#pragma unroll
    for (int e = 0; e < 4; ++e) {
        float mx = s[0][e];
#pragma unroll
        for (int fc = 1; fc < 6; ++fc) mx = fmaxf(mx, s[fc][e]);
#pragma unroll
        for (int off = 1; off < 16; off <<= 1) mx = fmaxf(mx, __shfl_xor(mx, off));
        mrow[e] = mx * 0.125f;
        lrow[e] = 0.f;
    }
    const int e0 = (l >> 4) * 4;
#pragma unroll
    for (int fc = 0; fc < 6; ++fc) {
#pragma unroll
        for (int e = 0; e < 4; ++e) {
            const float p = __expf(fmaf(s[fc][e], 0.125f, -mrow[e]));
            lrow[e] += p;
            Ps[16 * w + e0 + e][fc * 16 + fr] = f2bf(p);
        }
    }
#pragma unroll
    for (int e = 0; e < 4; ++e)
#pragma unroll
        for (int off = 1; off < 16; off <<= 1) lrow[e] += __shfl_xor(lrow[e], off);

    __syncthreads();

    f32x4 oacc[4] = {};
#pragma unroll
    for (int ks = 0; ks < 3; ++ks) {
        bf16x8 ap = *(const bf16x8*)&Ps[16 * w + fr][ks * 32 + fk];
#pragma unroll
        for (int j = 0; j < 4; ++j) {
            bf16x8 bv = *(const bf16x8*)&VT[j * 16 + fr][ks * 32 + fk];
            oacc[j] = __builtin_amdgcn_mfma_f32_16x16x32_bf16(ap, bv, oacc[j], 0, 0, 0);
        }
    }
    float mk[4];
#pragma unroll
    for (int e = 0; e < 4; ++e) {
        const size_t qrow = base + (size_t)(16 * w + e0 + e) * stride;
        mk[e] = mask[qrow] / lrow[e];
    }
#pragma unroll
    for (int j = 0; j < 4; ++j)
#pragma unroll
        for (int e = 0; e < 4; ++e) {
            const size_t qrow = base + (size_t)(16 * w + e0 + e) * stride;
            out[qrow * 512 + h * 64 + j * 16 + fr] = f2bf(oacc[j][e] * mk[e]);
        }
}

// ---------------- residual add + LayerNorm (one wave per row of 512) ----------------
template<typename TA, typename TB, typename TO>
__global__ __launch_bounds__(64)
void add_ln(const TA* __restrict__ a, const TB* __restrict__ bsrc,
            const float* __restrict__ g, const float* __restrict__ beta,
            TO* __restrict__ out)
{
    const size_t row = blockIdx.x;
    const int lane = threadIdx.x;
    float ya[8], yb[8], y[8];
    load8(a + row * D_ + lane * 8, ya);
    load8(bsrc + row * D_ + lane * 8, yb);
    float sum = 0.f, sq = 0.f;
#pragma unroll
    for (int i = 0; i < 8; ++i) { y[i] = ya[i] + yb[i]; sum += y[i]; sq += y[i] * y[i]; }
#pragma unroll
    for (int off = 32; off >= 1; off >>= 1) {
        sum += __shfl_xor(sum, off);
        sq  += __shfl_xor(sq, off);
    }
    const float mean = sum * (1.f / D_);
    const float var  = sq * (1.f / D_) - mean * mean;
    const float rstd = rsqrtf(var + EPS_);
    const float* gp = g + lane * 8;
    const float* bp = beta + lane * 8;
    float o[8];
#pragma unroll
    for (int i = 0; i < 8; ++i) o[i] = (y[i] - mean) * rstd * gp[i] + bp[i];
    store8(out + row * D_ + lane * 8, o);
}

extern "C" void kernel_launch(void* const* d_in, const int* in_sizes, int n_in,
                              void* d_out, int out_size, void* d_ws, size_t ws_size,
                              hipStream_t stream)
{
    const float* x     = (const float*)d_in[0];
    const float* mask  = (const float*)d_in[1];
    const float* t_w   = (const float*)d_in[2];
    const float* t_b   = (const float*)d_in[3];
    const float* s_w   = (const float*)d_in[4];
    const float* s_b   = (const float*)d_in[5];
    const float* fc_w1 = (const float*)d_in[6];
    const float* fc_b1 = (const float*)d_in[7];
    const float* fc_w2 = (const float*)d_in[8];
    const float* fc_b2 = (const float*)d_in[9];
    const float* ln1_g = (const float*)d_in[10];
    const float* ln1_b = (const float*)d_in[11];
    const float* ln2_g = (const float*)d_in[12];
    const float* ln2_b = (const float*)d_in[13];

    const size_t PG = (size_t)NROWS * 512;
    const size_t WTC = (size_t)2048 * 512 * 2;    // tail elements (4 MB): 8xDD or fc WTs
    if (ws_size < (PG * 3 + WTC) * sizeof(u16)) return;
    u16* O0   = (u16*)d_out;                      // d_out pages (scratch until final LN)
    u16* O1   = O0 + PG;
    u16* WS0  = (u16*)d_ws;
    u16* WS1  = WS0 + PG;
    u16* WS2  = WS1 + PG;
    u16* TAIL = WS0 + 3 * PG;                     // weight-transpose area

    const dim3 gblk(256);
    const dim3 g512(4, NROWS / 128);
    const dim3 qkv3grid(6, NROWS / 256);
    const dim3 h3grid(4, NROWS / 256);

    // x -> bf16 (WS2 = xb, persists through LN1)
    cvt_f32_bf16<<<dim3((unsigned)(PG / 2048)), gblk, 0, stream>>>(x, WS2);
    // all 8 square attn WTs -> tail: [t0,t1,t2,t3,s0,s1,s2,s3]
    tconv8<<<dim3(16, 16, 8), gblk, 0, stream>>>(t_w, s_w, TAIL);
    // time QKV: q->O0, k->WS0, v->WS1
    gemm3<0, u16><<<qkv3grid, dim3(512), 0, stream>>>(
        WS2, TAIL, t_b, O0, WS0, WS1, 512, 512, 512, 512, 9);
    attn_mfma<<<dim3(B_ * H_ * 96), dim3(384), 0, stream>>>(O0, WS0, WS1, mask, O0, 1);
    gemm2<0, false, u16><<<g512, gblk, 0, stream>>>(
        O0, TAIL + (size_t)3 * DD_, t_b + 3 * 512, O1, 512, 512, 512, 512);   // tt -> O1
    // space QKV (A = tt in O1)
    gemm3<0, u16><<<qkv3grid, dim3(512), 0, stream>>>(
        O1, TAIL + (size_t)4 * DD_, s_b, O0, WS0, WS1, 512, 512, 512, 512, 9);
    attn_mfma<<<dim3(B_ * H_ * 96), dim3(384), 0, stream>>>(O0, WS0, WS1, mask, O0, 0);
    gemm2<0, false, u16><<<g512, gblk, 0, stream>>>(
        O0, TAIL + (size_t)7 * DD_, s_b + 3 * 512, O1, 512, 512, 512, 512);   // ss -> O1
    // LN1: x1 = LN(xb + ss) -> WS2 in-place (per-row)
    add_ln<u16, u16, u16><<<dim3(NROWS), dim3(64), 0, stream>>>(WS2, O1, ln1_g, ln1_b, WS2);
    // fc WTs -> tail (square WTs dead)
    u16* WT1f = TAIL;                             // fc_w1^T (2048 x 512), 1M elems
    u16* WT2f = TAIL + (size_t)2048 * 512;        // fc_w2^T (512 x 2048), 1M elems
    tconv<<<dim3(64, 16), gblk, 0, stream>>>(fc_w1, WT1f, 512, 2048);
    tconv<<<dim3(16, 64), gblk, 0, stream>>>(fc_w2, WT2f, 2048, 512);
    // ---- FFN in 2 FF-chunks; disjoint read/write buffers per dispatch ----
    // chunk 0: hA = leaky(x1 @ W1[:,0:1024]) -> O0:O1 (rows x 1024 bf16)
    gemm3<1, u16><<<h3grid, dim3(512), 0, stream>>>(
        WS2, WT1f, fc_b1, O0, O0, O0, 512, 512, 512, 1024, 30);
    //          ffA = hA @ W2[0:1024,:] + b2 -> WS1 (reads d_out, writes d_ws)
    gemm2<0, false, u16><<<g512, gblk, 0, stream>>>(O0, WT2f, fc_b2, WS1, 1024, 1024, 2048, 512);
    // chunk 1: hB -> O0:O1 (overwrite; WS1 untouched)
    gemm3<1, u16><<<h3grid, dim3(512), 0, stream>>>(
        WS2, WT1f + (size_t)1024 * 512, fc_b1 + 1024, O0, O0, O0, 512, 512, 512, 1024, 30);
    //          ff += hB @ W2[1024:2048,:] -> WS1 in-place ACC
    gemm2<0, true, u16><<<g512, gblk, 0, stream>>>(O0, WT2f + 1024, nullptr, WS1, 1024, 1024, 2048, 512);
    // LN2: out = LN(x1 + ff) -> fp32 d_out (sources WS2/WS1 in d_ws only)
    add_ln<u16, u16, float><<<dim3(NROWS), dim3(64), 0, stream>>>(
        WS2, WS1, ln2_g, ln2_b, (float*)d_out);
}

// Round 10
// 553.410 us; speedup vs baseline: 8.3462x; 1.0273x over previous
//
#include <hip/hip_runtime.h>
#include <hip/hip_bf16.h>

#define B_ 4
#define S_ 96
#define T_ 96
#define D_ 512
#define H_ 8
#define FF_ 2048
#define NROWS (B_*S_*T_)   // 36864
#define EPS_ 1e-5f
#define NEG_ 0.01f
#define DD_ (512*512)

typedef unsigned short u16;   // bf16 bits
typedef __attribute__((ext_vector_type(8))) short bf16x8;
typedef __attribute__((ext_vector_type(4))) float f32x4;
typedef __attribute__((address_space(1))) const unsigned glb_u32;
typedef __attribute__((address_space(3))) unsigned lds_u32;

__device__ __forceinline__ float bf(u16 u) { return __uint_as_float(((unsigned)u) << 16); }
__device__ __forceinline__ u16 f2bf(float f) {
    __hip_bfloat16 h = __float2bfloat16(f);
    return *reinterpret_cast<u16*>(&h);
}
__device__ __forceinline__ float blo(unsigned v) { return __uint_as_float(v << 16); }
__device__ __forceinline__ float bhi(unsigned v) { return __uint_as_float(v & 0xffff0000u); }

__device__ __forceinline__ float cvt_ld(float x) { return x; }
__device__ __forceinline__ float cvt_ld(u16 x)  { return bf(x); }
__device__ __forceinline__ void cvt_st(float* p, float v) { *p = v; }
__device__ __forceinline__ void cvt_st(u16* p, float v)   { *p = f2bf(v); }

__device__ __forceinline__ void load8(const float* p, float* y) {
    float4 a = *(const float4*)p, b = *(const float4*)(p + 4);
    y[0]=a.x; y[1]=a.y; y[2]=a.z; y[3]=a.w; y[4]=b.x; y[5]=b.y; y[6]=b.z; y[7]=b.w;
}
__device__ __forceinline__ void load8(const u16* p, float* y) {
    uint4 u = *(const uint4*)p;
    y[0]=blo(u.x); y[1]=bhi(u.x); y[2]=blo(u.y); y[3]=bhi(u.y);
    y[4]=blo(u.z); y[5]=bhi(u.z); y[6]=blo(u.w); y[7]=bhi(u.w);
}
__device__ __forceinline__ void store8(float* p, const float* y) {
    *(float4*)p       = make_float4(y[0], y[1], y[2], y[3]);
    *(float4*)(p + 4) = make_float4(y[4], y[5], y[6], y[7]);
}
__device__ __forceinline__ void store8(u16* p, const float* y) {
    ushort4 a, b;
    a.x = f2bf(y[0]); a.y = f2bf(y[1]); a.z = f2bf(y[2]); a.w = f2bf(y[3]);
    b.x = f2bf(y[4]); b.y = f2bf(y[5]); b.z = f2bf(y[6]); b.w = f2bf(y[7]);
    *(ushort4*)p = a; *(ushort4*)(p + 4) = b;
}

// ---------------- fp32 -> bf16 elementwise ----------------
__global__ __launch_bounds__(256)
void cvt_f32_bf16(const float* __restrict__ in, u16* __restrict__ out)
{
    const size_t i = ((size_t)blockIdx.x * 256 + threadIdx.x) * 8;
    float y[8];
    load8(in + i, y);
    store8(out + i, y);
}

// ---------------- transpose + convert (generic) ----------------
__global__ __launch_bounds__(256)
void tconv(const float* __restrict__ in, u16* __restrict__ out, int R, int C)
{
    __shared__ float t[32][33];
    const int c0 = blockIdx.x * 32, r0 = blockIdx.y * 32;
    const int tr = threadIdx.x >> 3, c4 = (threadIdx.x & 7) * 4;
    float4 v = *(const float4*)(in + (size_t)(r0 + tr) * C + c0 + c4);
    t[tr][c4] = v.x; t[tr][c4 + 1] = v.y; t[tr][c4 + 2] = v.z; t[tr][c4 + 3] = v.w;
    __syncthreads();
    const int oc = tr, r4 = c4;
    ushort4 u;
    u.x = f2bf(t[r4 + 0][oc]); u.y = f2bf(t[r4 + 1][oc]);
    u.z = f2bf(t[r4 + 2][oc]); u.w = f2bf(t[r4 + 3][oc]);
    *(ushort4*)(out + (size_t)(c0 + oc) * R + r0 + r4) = u;
}

// ---------------- batched 512x512 weight prep -> tail ----------------
// slots [t0^T, t1^T, t2^T, t3 PLAIN, s0^T, s1^T, s2^T, s3^T]
// (slot 3 is kept NON-transposed bf16: it is the WT operand of the fused-weight GEMM)
__global__ __launch_bounds__(256)
void tconv8(const float* __restrict__ t_w, const float* __restrict__ s_w,
            u16* __restrict__ out)
{
    __shared__ float t[32][33];
    const int z = blockIdx.z;
    const float* in = (z < 4) ? (t_w + (size_t)z * DD_) : (s_w + (size_t)(z - 4) * DD_);
    u16* o = out + (size_t)z * DD_;
    const int c0 = blockIdx.x * 32, r0 = blockIdx.y * 32;
    const int tr = threadIdx.x >> 3, c4 = (threadIdx.x & 7) * 4;
    float4 v = *(const float4*)(in + (size_t)(r0 + tr) * 512 + c0 + c4);
    if (z == 3) {   // plain convert-copy (uniform per block; no sync hazards)
        ushort4 u;
        u.x = f2bf(v.x); u.y = f2bf(v.y); u.z = f2bf(v.z); u.w = f2bf(v.w);
        *(ushort4*)(o + (size_t)(r0 + tr) * 512 + c0 + c4) = u;
        return;
    }
    t[tr][c4] = v.x; t[tr][c4 + 1] = v.y; t[tr][c4 + 2] = v.z; t[tr][c4 + 3] = v.w;
    __syncthreads();
    const int oc = tr, r4 = c4;
    ushort4 u;
    u.x = f2bf(t[r4 + 0][oc]); u.y = f2bf(t[r4 + 1][oc]);
    u.z = f2bf(t[r4 + 2][oc]); u.w = f2bf(t[r4 + 3][oc]);
    *(ushort4*)(o + (size_t)(c0 + oc) * 512 + r0 + r4) = u;
}

// ---------------- fused bias: fb[i*512+n] = s_b[i][n] + dot(WTs_i[n][:], t_b3) ----------------
__global__ __launch_bounds__(256)
void fbias_k(const u16* __restrict__ WTs, const float* __restrict__ tb3,
             const float* __restrict__ sb, float* __restrict__ fb)
{
    const int j = blockIdx.x * 256 + threadIdx.x;   // 0..1535
    const u16* row = WTs + (size_t)j * 512;         // [1536][512] (slots s0,s1,s2)
    float acc = sb[j];
    for (int k = 0; k < 512; k += 8) {
        float y[8], t[8];
        load8(row + k, y);
        load8(tb3 + k, t);
        acc += y[0]*t[0] + y[1]*t[1] + y[2]*t[2] + y[3]*t[3]
             + y[4]*t[4] + y[5]*t[5] + y[6]*t[6] + y[7]*t[7];
    }
    fb[j] = acc;
}

// ======== 128^2 GEMM (verified rounds 6-9): single-buffer 32 KB,
// XOR bank-deswizzle (both-sides), XCD-chunked grid swizzle ========
#define GEMM_PRE()                                                              \
    const int tid = threadIdx.x;                                                \
    const int w = tid >> 6, l = tid & 63;                                       \
    const int wr = w >> 1, wc = w & 1;                                          \
    const unsigned gx = gridDim.x;                                              \
    const unsigned nwg = gx * gridDim.y;                                        \
    unsigned f = blockIdx.y * gx + blockIdx.x;                                  \
    f = (f & 7) * (nwg >> 3) + (f >> 3);                                        \
    const int lrow = l >> 3;                                                    \
    const int swz8 = (((l & 7) ^ lrow) << 3);                                   \
    const int fr16 = l & 15;                                                    \
    const int kq = l >> 4;

#define GEMM_COMPUTE()                                                          \
    _Pragma("unroll")                                                           \
    for (int kk = 0; kk < 2; ++kk) {                                            \
        const int sw = ((((kk << 2) | kq)) ^ (fr16 & 7)) << 3;                  \
        bf16x8 af[4], bfr[4];                                                   \
        _Pragma("unroll")                                                       \
        for (int i = 0; i < 4; ++i)                                             \
            af[i] = *(bf16x8*)&As[(wr * 64 + i * 16 + fr16) * 64 + sw];         \
        _Pragma("unroll")                                                       \
        for (int j = 0; j < 4; ++j)                                             \
            bfr[j] = *(bf16x8*)&Bs[(wc * 64 + j * 16 + fr16) * 64 + sw];        \
        _Pragma("unroll")                                                       \
        for (int i = 0; i < 4; ++i)                                             \
            _Pragma("unroll")                                                   \
            for (int j = 0; j < 4; ++j)                                         \
                acc[i][j] = __builtin_amdgcn_mfma_f32_16x16x32_bf16(af[i], bfr[j], acc[i][j], 0, 0, 0); \
    }

// ACT: 0 = bias, 1 = bias+leaky, 2 = no-bias
template<int ACT, bool ACC, typename TC>
__global__ __launch_bounds__(256)
void gemm2(const u16* __restrict__ A, const u16* __restrict__ WT,
           const float* __restrict__ bias, TC* __restrict__ C,
           int K, int lda, int ldwt, int ldc)
{
    __shared__ u16 As[128 * 64];
    __shared__ u16 Bs[128 * 64];
    GEMM_PRE();
    const int row0 = (int)(f / gx) * 128, col0 = (int)(f % gx) * 128;
    f32x4 acc[4][4] = {};

    for (int kt = 0; kt < K; kt += 64) {
#pragma unroll
        for (int j = 0; j < 4; ++j) {
            const int line = w * 32 + j * 8;
            const u16* asrc = A  + (size_t)(row0 + line + lrow) * lda  + kt + swz8;
            const u16* bsrc = WT + (size_t)(col0 + line + lrow) * ldwt + kt + swz8;
            __builtin_amdgcn_global_load_lds((glb_u32*)asrc, (lds_u32*)&As[line * 64], 16, 0, 0);
            __builtin_amdgcn_global_load_lds((glb_u32*)bsrc, (lds_u32*)&Bs[line * 64], 16, 0, 0);
        }
        __syncthreads();
        GEMM_COMPUTE();
        __syncthreads();
    }
    const int crow = kq * 4;
#pragma unroll
    for (int i = 0; i < 4; ++i)
#pragma unroll
        for (int j = 0; j < 4; ++j) {
            const int col = col0 + wc * 64 + j * 16 + fr16;
            const float bv = (ACC || ACT == 2) ? 0.f : bias[col];
#pragma unroll
            for (int e = 0; e < 4; ++e) {
                const size_t r = (size_t)(row0 + wr * 64 + i * 16 + crow + e);
                TC* cp = &C[r * (size_t)ldc + col];
                float v = acc[i][j][e] + bv;
                if (ACC) v += cvt_ld(*cp);
                if (ACT == 1) v = (v >= 0.f) ? v : NEG_ * v;
                cvt_st(cp, v);
            }
        }
}

// ================= gemm3: 256x256, BK=64, dbuf + counted vmcnt + 4-phase (verified r9) ==========
template<int ACT, typename TC>
__global__ __launch_bounds__(512)
void gemm3(const u16* __restrict__ A, const u16* __restrict__ WT,
           const float* __restrict__ bias,
           TC* __restrict__ p0, TC* __restrict__ p1, TC* __restrict__ p2,
           int K, int lda, int ldwt, int ldc, int pgshift)
{
    __shared__ u16 lds[65536];   // 128 KB
    const int tid = threadIdx.x;
    const int w = tid >> 6, l = tid & 63;
    const int wr = w >> 2, wc = w & 3;
    const unsigned gx = gridDim.x;
    const unsigned nwg = gx * gridDim.y;
    unsigned f = blockIdx.y * gx + blockIdx.x;
    f = (f & 7) * (nwg >> 3) + (f >> 3);
    const int row0 = (int)(f / gx) * 256, colg0 = (int)(f % gx) * 256;
    const int lrow = l >> 3;
    const int swz8 = (((l & 7) ^ lrow) << 3);
    const int fr16 = l & 15;
    const int kq = l >> 4;

    f32x4 acc[8][4] = {};
    const int NT = K >> 6;

    auto stage = [&](int buf, int kt) {
        u16* Ad = lds + buf * 16384;
        u16* Bd = lds + 32768 + buf * 16384;
#pragma unroll
        for (int j = 0; j < 4; ++j) {
            const int lineb = j * 64 + w * 8;
            const int srow = lineb + lrow;
            const u16* asrc = A  + (size_t)(row0  + srow) * lda  + kt + swz8;
            const u16* bsrc = WT + (size_t)(colg0 + srow) * ldwt + kt + swz8;
            __builtin_amdgcn_global_load_lds((glb_u32*)asrc, (lds_u32*)&Ad[lineb * 64], 16, 0, 0);
            __builtin_amdgcn_global_load_lds((glb_u32*)bsrc, (lds_u32*)&Bd[lineb * 64], 16, 0, 0);
        }
    };

    stage(0, 0);
    for (int t = 0; t < NT; ++t) {
        const int cur = t & 1;
        if (t + 1 < NT) {
            stage(cur ^ 1, (t + 1) << 6);
            asm volatile("s_waitcnt vmcnt(8)" ::: "memory");
        } else {
            asm volatile("s_waitcnt vmcnt(0)" ::: "memory");
        }
        __builtin_amdgcn_s_barrier();                     // gate: buf[cur] published
        const u16* Ab = lds + cur * 16384;
        const u16* Bb = lds + 32768 + cur * 16384;
        bf16x8 bq[4];
#pragma unroll
        for (int p = 0; p < 4; ++p) {
            const int kk = p >> 1, ih = p & 1;
            const int sw = ((((kk << 2) | kq)) ^ (fr16 & 7)) << 3;
            if (ih == 0) {
#pragma unroll
                for (int j = 0; j < 4; ++j)
                    bq[j] = *(bf16x8*)&Bb[(wc * 64 + j * 16 + fr16) * 64 + sw];
            }
            bf16x8 af[4];
#pragma unroll
            for (int i = 0; i < 4; ++i)
                af[i] = *(bf16x8*)&Ab[(wr * 128 + (ih * 4 + i) * 16 + fr16) * 64 + sw];
            __builtin_amdgcn_s_barrier();                 // phase alignment
            __builtin_amdgcn_s_setprio(1);
#pragma unroll
            for (int i = 0; i < 4; ++i)
#pragma unroll
                for (int j = 0; j < 4; ++j)
                    acc[ih * 4 + i][j] = __builtin_amdgcn_mfma_f32_16x16x32_bf16(
                        af[i], bq[j], acc[ih * 4 + i][j], 0, 0, 0);
            __builtin_amdgcn_s_setprio(0);
        }
    }
    const int crow = kq * 4;
#pragma unroll
    for (int i = 0; i < 8; ++i)
#pragma unroll
        for (int j = 0; j < 4; ++j) {
            const int colg = colg0 + wc * 64 + j * 16 + fr16;
            TC* Cb = (((unsigned)colg >> pgshift) == 0) ? p0
                   : (((unsigned)colg >> pgshift) == 1) ? p1 : p2;
            const int col = colg & ((1 << pgshift) - 1);
            const float bv = bias[colg];
#pragma unroll
            for (int e = 0; e < 4; ++e) {
                const size_t r = (size_t)(row0 + wr * 128 + i * 16 + crow + e);
                float v = acc[i][j][e] + bv;
                if (ACT == 1) v = (v >= 0.f) ? v : NEG_ * v;
                cvt_st(&Cb[r * (size_t)ldc + col], v);
            }
        }
}

// ---------------- MFMA attention (rounds 4-9, verified, unchanged) ----------------
__global__ __launch_bounds__(384)
void attn_mfma(const u16* __restrict__ q, const u16* __restrict__ kbuf,
               const u16* __restrict__ vbuf, const float* __restrict__ mask,
               u16* __restrict__ out, int time_axis)
{
    __shared__ __align__(16) u16 Ks[96][72];
    __shared__ __align__(16) u16 VT[64][104];
    __shared__ __align__(16) u16 Ps[96][104];
    const int g = blockIdx.x;
    const int h = g & 7;
    const int bs = g >> 3;
    const int b = bs / 96, st = bs % 96;
    const size_t base   = time_axis ? ((size_t)(b * 96 + st) * 96) : ((size_t)b * 9216 + st);
    const size_t stride = time_axis ? 1 : 96;
    const int tid = threadIdx.x;
    const int w = tid / 64, l = tid & 63;
    const int fr = l & 15, fk = (l >> 4) * 8;

    for (int task = tid; task < 96 * 8; task += 384) {
        const int r = task >> 3, c = task & 7;
        *(uint4*)&Ks[r][c * 8] =
            *(const uint4*)(kbuf + (base + (size_t)r * stride) * 512 + h * 64 + c * 8);
    }
    for (int task = tid; task < 96 * 8; task += 384) {
        const int r = task >> 3, c = task & 7;
        uint4 dv = *(const uint4*)(vbuf + (base + (size_t)r * stride) * 512 + h * 64 + c * 8);
        const u16* e = (const u16*)&dv;
#pragma unroll
        for (int j = 0; j < 8; ++j) VT[c * 8 + j][r] = e[j];
    }
    const u16* qp = q + (base + (size_t)(16 * w + fr) * stride) * 512 + h * 64;
    bf16x8 aq0 = *(const bf16x8*)(qp + fk);
    bf16x8 aq1 = *(const bf16x8*)(qp + 32 + fk);
    __syncthreads();

    f32x4 s[6] = {};
#pragma unroll
    for (int fc = 0; fc < 6; ++fc) {
        bf16x8 b0 = *(const bf16x8*)&Ks[fc * 16 + fr][fk];
        bf16x8 b1 = *(const bf16x8*)&Ks[fc * 16 + fr][32 + fk];
        s[fc] = __builtin_amdgcn_mfma_f32_16x16x32_bf16(aq0, b0, s[fc], 0, 0, 0);
        s[fc] = __builtin_amdgcn_mfma_f32_16x16x32_bf16(aq1, b1, s[fc], 0, 0, 0);
    }
    float mrow[4], lrow[4];
#pragma unroll
    for (int e = 0; e < 4; ++e) {
        float mx = s[0][e];
#pragma unroll
        for (int fc = 1; fc < 6; ++fc) mx = fmaxf(mx, s[fc][e]);
#pragma unroll
        for (int off = 1; off < 16; off <<= 1) mx = fmaxf(mx, __shfl_xor(mx, off));
        mrow[e] = mx * 0.125f;
        lrow[e] = 0.f;
    }
    const int e0 = (l >> 4) * 4;
#pragma unroll
    for (int fc = 0; fc < 6; ++fc) {
#pragma unroll
        for (int e = 0; e < 4; ++e) {
            const float p = __expf(fmaf(s[fc][e], 0.125f, -mrow[e]));
            lrow[e] += p;
            Ps[16 * w + e0 + e][fc * 16 + fr] = f2bf(p);
        }
    }
#pragma unroll
    for (int e = 0; e < 4; ++e)
#pragma unroll
        for (int off = 1; off < 16; off <<= 1) lrow[e] += __shfl_xor(lrow[e], off);

    __syncthreads();

    f32x4 oacc[4] = {};
#pragma unroll
    for (int ks = 0; ks < 3; ++ks) {
        bf16x8 ap = *(const bf16x8*)&Ps[16 * w + fr][ks * 32 + fk];
#pragma unroll
        for (int j = 0; j < 4; ++j) {
            bf16x8 bv = *(const bf16x8*)&VT[j * 16 + fr][ks * 32 + fk];
            oacc[j] = __builtin_amdgcn_mfma_f32_16x16x32_bf16(ap, bv, oacc[j], 0, 0, 0);
        }
    }
    float mk[4];
#pragma unroll
    for (int e = 0; e < 4; ++e) {
        const size_t qrow = base + (size_t)(16 * w + e0 + e) * stride;
        mk[e] = mask[qrow] / lrow[e];
    }
#pragma unroll
    for (int j = 0; j < 4; ++j)
#pragma unroll
        for (int e = 0; e < 4; ++e) {
            const size_t qrow = base + (size_t)(16 * w + e0 + e) * stride;
            out[qrow * 512 + h * 64 + j * 16 + fr] = f2bf(oacc[j][e] * mk[e]);
        }
}

// ---------------- residual add + LayerNorm (one wave per row of 512) ----------------
template<typename TA, typename TB, typename TO>
__global__ __launch_bounds__(64)
void add_ln(const TA* __restrict__ a, const TB* __restrict__ bsrc,
            const float* __restrict__ g, const float* __restrict__ beta,
            TO* __restrict__ out)
{
    const size_t row = blockIdx.x;
    const int lane = threadIdx.x;
    float ya[8], yb[8], y[8];
    load8(a + row * D_ + lane * 8, ya);
    load8(bsrc + row * D_ + lane * 8, yb);
    float sum = 0.f, sq = 0.f;
#pragma unroll
    for (int i = 0; i < 8; ++i) { y[i] = ya[i] + yb[i]; sum += y[i]; sq += y[i] * y[i]; }
#pragma unroll
    for (int off = 32; off >= 1; off >>= 1) {
        sum += __shfl_xor(sum, off);
        sq  += __shfl_xor(sq, off);
    }
    const float mean = sum * (1.f / D_);
    const float var  = sq * (1.f / D_) - mean * mean;
    const float rstd = rsqrtf(var + EPS_);
    const float* gp = g + lane * 8;
    const float* bp = beta + lane * 8;
    float o[8];
#pragma unroll
    for (int i = 0; i < 8; ++i) o[i] = (y[i] - mean) * rstd * gp[i] + bp[i];
    store8(out + row * D_ + lane * 8, o);
}

extern "C" void kernel_launch(void* const* d_in, const int* in_sizes, int n_in,
                              void* d_out, int out_size, void* d_ws, size_t ws_size,
                              hipStream_t stream)
{
    const float* x     = (const float*)d_in[0];
    const float* mask  = (const float*)d_in[1];
    const float* t_w   = (const float*)d_in[2];
    const float* t_b   = (const float*)d_in[3];
    const float* s_w   = (const float*)d_in[4];
    const float* s_b   = (const float*)d_in[5];
    const float* fc_w1 = (const float*)d_in[6];
    const float* fc_b1 = (const float*)d_in[7];
    const float* fc_w2 = (const float*)d_in[8];
    const float* fc_b2 = (const float*)d_in[9];
    const float* ln1_g = (const float*)d_in[10];
    const float* ln1_b = (const float*)d_in[11];
    const float* ln2_g = (const float*)d_in[12];
    const float* ln2_b = (const float*)d_in[13];

    const size_t PG = (size_t)NROWS * 512;
    const size_t WTC = (size_t)2048 * 512 * 2;    // tail (4 MB): 8xDD slots or fc WTs
    if (ws_size < (PG * 3 + WTC) * sizeof(u16)) return;
    u16* O0   = (u16*)d_out;                      // d_out pages (scratch until final LN)
    u16* O1   = O0 + PG;
    u16* WS0  = (u16*)d_ws;
    u16* WS1  = WS0 + PG;
    u16* WS2  = WS1 + PG;
    u16* TAIL = WS0 + 3 * PG;

    const dim3 gblk(256);
    const dim3 g512(4, NROWS / 128);
    const dim3 qkv3grid(6, NROWS / 256);
    const dim3 h3grid(8, 72);                     // M=18432, N=2048

    // x -> bf16 (WS2 = xb, persists through LN1)
    cvt_f32_bf16<<<dim3((unsigned)(PG / 2048)), gblk, 0, stream>>>(x, WS2);
    // weight prep: slots [t0^T,t1^T,t2^T, t3 PLAIN, s0^T,s1^T,s2^T,s3^T]
    tconv8<<<dim3(16, 16, 8), gblk, 0, stream>>>(t_w, s_w, TAIL);
    // time QKV: q->O0, k->WS0, v->WS1 (reads slots 0-2)
    gemm3<0, u16><<<qkv3grid, dim3(512), 0, stream>>>(
        WS2, TAIL, t_b, O0, WS0, WS1, 512, 512, 512, 512, 9);
    // fused weights: WTf[1536][512] = WTs_{0..2} @ t_w3(plain)  -> slots 0-2 (dead after qkv)
    gemm2<2, false, u16><<<dim3(4, 12), gblk, 0, stream>>>(
        TAIL + (size_t)4 * DD_, TAIL + (size_t)3 * DD_, nullptr, TAIL, 512, 512, 512, 512);
    // fused bias -> fp32[1536] at slot-3 bytes (plain t_w3 dead after gemmW)
    float* fb = (float*)(TAIL + (size_t)3 * DD_);
    fbias_k<<<dim3(6), gblk, 0, stream>>>(TAIL + (size_t)4 * DD_, t_b + 3 * 512, s_b, fb);
    // time attention: (O0,WS0,WS1) -> O0
    attn_mfma<<<dim3(B_ * H_ * 96), dim3(384), 0, stream>>>(O0, WS0, WS1, mask, O0, 1);
    // space QKV directly from time-attn output (tt GEMM eliminated): q->O1, k->WS0, v->WS1
    gemm3<0, u16><<<qkv3grid, dim3(512), 0, stream>>>(
        O0, TAIL, fb, O1, WS0, WS1, 512, 512, 512, 512, 9);
    // space attention: (O1,WS0,WS1) -> O0  (read q from O1, write O0: fully disjoint)
    attn_mfma<<<dim3(B_ * H_ * 96), dim3(384), 0, stream>>>(O1, WS0, WS1, mask, O0, 0);
    // ss projection: O0 @ s_w3 -> O1 (slot 7)
    gemm2<0, false, u16><<<g512, gblk, 0, stream>>>(
        O0, TAIL + (size_t)7 * DD_, s_b + 3 * 512, O1, 512, 512, 512, 512);
    // LN1: x1 = LN(xb + ss) -> WS2 in-place
    add_ln<u16, u16, u16><<<dim3(NROWS), dim3(64), 0, stream>>>(WS2, O1, ln1_g, ln1_b, WS2);
    // fc WTs -> tail (all slots dead now)
    u16* WT1f = TAIL;                             // fc_w1^T (2048 x 512)
    u16* WT2f = TAIL + (size_t)2048 * 512;        // fc_w2^T (512 x 2048)
    tconv<<<dim3(64, 16), gblk, 0, stream>>>(fc_w1, WT1f, 512, 2048);
    tconv<<<dim3(16, 64), gblk, 0, stream>>>(fc_w2, WT2f, 2048, 512);
    // ---- FFN row-split: per half, h fills d_out (2048-wide), single-pass ff -> WS1 ----
    for (int r = 0; r < 2; ++r) {
        const size_t off = (size_t)r * 18432;
        // h = leaky(x1 @ W1 + b1): [18432][2048] -> O0 (ldc 2048, fills d_out exactly)
        gemm3<1, u16><<<h3grid, dim3(512), 0, stream>>>(
            WS2 + off * 512, WT1f, fc_b1, O0, O0, O0, 512, 512, 512, 2048, 30);
        // ff = h @ W2 + b2: K=2048 single pass (reads d_out, writes d_ws: disjoint)
        gemm2<0, false, u16><<<dim3(4, 144), gblk, 0, stream>>>(
            O0, WT2f, fc_b2, WS1 + off * 512, 2048, 2048, 2048, 512);
    }
    // LN2: out = LN(x1 + ff) -> fp32 d_out (sources WS2/WS1 in d_ws only)
    add_ln<u16, u16, float><<<dim3(NROWS), dim3(64), 0, stream>>>(
        WS2, WS1, ln2_g, ln2_b, (float*)d_out);
}